// Round 2
// baseline (2045.548 us; speedup 1.0000x reference)
//
#include <hip/hip_runtime.h>

// Sizes
#define HB 256      // batch
#define HC 128      // channels
#define HN 729      // 27*27 tokens
#define NP 732      // padded token pitch (multiple of 4 -> 16B-aligned rows)

__device__ __forceinline__ float wsum(float v) {
    #pragma unroll
    for (int m = 32; m >= 1; m >>= 1) v += __shfl_xor(v, m, 64);
    return v;
}

// ---------------------------------------------------------------- weight prep
// w1ft[i*64+o]            = w_ffn1[o*256+i]           (16384)
// w2ft[j*128+c]           = w_ffn2[c*64+j]            (8192)
// w1t[(ic*9+t)*64+oc]     = w_c1[(oc*128+ic)*9+t]     (73728)
// w2t[(ic*9+t)*128+oc]    = w_c2[(oc*64+ic)*9+t]      (73728)
__global__ void k_prep(const float* __restrict__ wf1, const float* __restrict__ wf2,
                       const float* __restrict__ wc1, const float* __restrict__ wc2,
                       float* __restrict__ w1ft, float* __restrict__ w2ft,
                       float* __restrict__ w1t, float* __restrict__ w2t)
{
    int idx = blockIdx.x*256 + threadIdx.x;
    if (idx < 16384) {
        int i = idx >> 6, o = idx & 63;
        w1ft[idx] = wf1[o*256 + i];
    } else if (idx < 24576) {
        int t = idx - 16384; int j = t >> 7, c = t & 127;
        w2ft[t] = wf2[c*64 + j];
    } else if (idx < 98304) {
        int t = idx - 24576; int row = t >> 6, oc = t & 63;
        int ic = row/9, tap = row - ic*9;
        w1t[t] = wc1[(oc*128 + ic)*9 + tap];
    } else if (idx < 172032) {
        int t = idx - 98304; int row = t >> 7, oc = t & 127;
        int ic = row/9, tap = row - ic*9;
        w2t[t] = wc2[(oc*64 + ic)*9 + tap];
    }
}

// ---------------------------------------------------------------- qkv projection
// t[n,c] = x[b,c,n];  qkv = t @ wqkv + b
// q -> q2 buffer [B,C,NP] (channel-major); k,v -> [B,N,C] token-major
__global__ __launch_bounds__(256) void k_qkv(
    const float* __restrict__ x, const float* __restrict__ wqkv, const float* __restrict__ bqkv,
    float* __restrict__ q2, float* __restrict__ k2, float* __restrict__ v)
{
    __shared__ __align__(16) float A[128*64];
    __shared__ __align__(16) float W[128*64];
    const int b = blockIdx.y;
    const int n0 = blockIdx.x * 64;
    const int tid = threadIdx.x;
    const int tq = tid & 15, og = tid >> 4;
    for (int idx = tid; idx < 128*64; idx += 256) {
        int c = idx >> 6, j = idx & 63;
        int n = n0 + j;
        A[idx] = (n < HN) ? x[(size_t)(b*128 + c)*HN + n] : 0.f;
    }
    const bool full = (n0 + 64 <= HN);
    for (int ch = 0; ch < 6; ++ch) {
        __syncthreads();
        for (int idx = tid; idx < 128*64; idx += 256) {
            int kk = idx >> 6, o = idx & 63;
            W[idx] = wqkv[kk*384 + ch*64 + o];
        }
        __syncthreads();
        float acc[4][4];
        #pragma unroll
        for (int i = 0; i < 4; ++i)
            #pragma unroll
            for (int jj = 0; jj < 4; ++jj) acc[i][jj] = bqkv[ch*64 + og*4 + jj];
        for (int kk = 0; kk < 128; ++kk) {
            float4 a = *(const float4*)&A[kk*64 + tq*4];
            float4 w = *(const float4*)&W[kk*64 + og*4];
            float av[4] = {a.x,a.y,a.z,a.w};
            float wv[4] = {w.x,w.y,w.z,w.w};
            #pragma unroll
            for (int i = 0; i < 4; ++i)
                #pragma unroll
                for (int jj = 0; jj < 4; ++jj) acc[i][jj] += av[i]*wv[jj];
        }
        if (ch < 2) {
            if (full) {
                #pragma unroll
                for (int jj = 0; jj < 4; ++jj) {
                    int o = ch*64 + og*4 + jj;
                    float4 o4 = make_float4(acc[0][jj], acc[1][jj], acc[2][jj], acc[3][jj]);
                    *(float4*)&q2[(size_t)(b*128 + o)*NP + n0 + tq*4] = o4;
                }
            } else {
                for (int i = 0; i < 4; ++i) {
                    int n = n0 + tq*4 + i;
                    if (n < HN)
                        for (int jj = 0; jj < 4; ++jj) {
                            int o = ch*64 + og*4 + jj;
                            q2[(size_t)(b*128 + o)*NP + n] = acc[i][jj];
                        }
                }
            }
        } else {
            float* dst = (ch < 4) ? k2 : v;
            int off = (ch & 1)*64 + og*4;
            #pragma unroll
            for (int i = 0; i < 4; ++i) {
                int n = n0 + tq*4 + i;
                if (n < HN) {
                    float4 o4 = make_float4(acc[i][0], acc[i][1], acc[i][2], acc[i][3]);
                    *(float4*)&dst[((size_t)b*HN + n)*128 + off] = o4;
                }
            }
        }
    }
}

// ---------------------------------------------------------------- q postprocess (channel-major)
// q2 <- normalized((q-mean)^2 / (sum+1e-7)) per token; 3 strided-coalesced passes
__global__ __launch_bounds__(256) void k_post_q(float* __restrict__ q2)
{
    const int b = blockIdx.y;
    const int n = blockIdx.x*256 + threadIdx.x;
    if (n >= HN) return;
    float* p = q2 + (size_t)b*128*NP + n;
    float s1 = 0.f;
    for (int c = 0; c < 128; ++c) s1 += p[(size_t)c*NP];
    float m = s1 * (1.f/128.f);
    float s2 = 0.f, s4 = 0.f;
    for (int c = 0; c < 128; ++c) { float a = p[(size_t)c*NP] - m; float a2 = a*a; s2 += a2; s4 += a2*a2; }
    float invS = 1.f / (s2 + 1e-7f);
    float nrm = sqrtf(s4) * invS;           // ||q2_pre||_2
    float sc = invS / fmaxf(nrm, 1e-12f);
    for (int c = 0; c < 128; ++c) { float a = p[(size_t)c*NP] - m; p[(size_t)c*NP] = a*a*sc; }
}

// ---------------------------------------------------------------- k postprocess (token-major, wave per row)
__global__ __launch_bounds__(256) void k_post_k(float* __restrict__ k2)
{
    const size_t row = (size_t)blockIdx.x*4 + (threadIdx.x >> 6);
    const int lane = threadIdx.x & 63;
    float* p = k2 + row*128;
    float a0 = p[lane], a1 = p[lane+64];
    float m = wsum(a0+a1) * (1.f/128.f);
    a0 -= m; a1 -= m; a0 *= a0; a1 *= a1;
    float S = wsum(a0+a1);
    float invS = 1.f/(S + 1e-7f);
    p[lane] = a0*invS; p[lane+64] = a1*invS;
}

// ---------------------------------------------------------------- column norms of k2 over tokens (fold into kv)
__global__ __launch_bounds__(128) void k_colnorm(const float* __restrict__ k2, float* __restrict__ cn)
{
    const int b = blockIdx.x, c = threadIdx.x;
    const float* p = k2 + (size_t)b*HN*128 + c;
    float s = 0.f;
    for (int n = 0; n < HN; ++n) { float t = p[(size_t)n*128]; s += t*t; }
    cn[b*128 + c] = 1.f / fmaxf(sqrtf(s), 1e-12f);
}

// ---------------------------------------------------------------- kv[b,c,d] = invcol[c] * sum_n k2[b,n,c] v[b,n,d]
__global__ __launch_bounds__(256) void k_kv(const float* __restrict__ k2, const float* __restrict__ v,
                                            const float* __restrict__ cn, float* __restrict__ kv)
{
    __shared__ __align__(16) float Kt[64*128];
    __shared__ __align__(16) float Vt[64*128];
    const int b = blockIdx.x, tid = threadIdx.x;
    const int ci = tid >> 4, di = tid & 15;
    float acc[8][8] = {};
    for (int n0 = 0; n0 < HN; n0 += 64) {
        __syncthreads();
        for (int idx = tid; idx < 64*128; idx += 256) {
            int j = idx >> 7, c = idx & 127;
            int n = n0 + j;
            float kk = 0.f, vv = 0.f;
            if (n < HN) {
                size_t base = ((size_t)b*HN + n)*128 + c;
                kk = k2[base]; vv = v[base];
            }
            Kt[idx] = kk; Vt[idx] = vv;
        }
        __syncthreads();
        for (int j = 0; j < 64; ++j) {
            float4 a0 = *(const float4*)&Kt[j*128 + ci*8];
            float4 a1 = *(const float4*)&Kt[j*128 + ci*8 + 4];
            float4 b0 = *(const float4*)&Vt[j*128 + di*8];
            float4 b1 = *(const float4*)&Vt[j*128 + di*8 + 4];
            float av[8] = {a0.x,a0.y,a0.z,a0.w,a1.x,a1.y,a1.z,a1.w};
            float bv[8] = {b0.x,b0.y,b0.z,b0.w,b1.x,b1.y,b1.z,b1.w};
            #pragma unroll
            for (int i = 0; i < 8; ++i)
                #pragma unroll
                for (int jj = 0; jj < 8; ++jj)
                    acc[i][jj] += av[i]*bv[jj];
        }
    }
    #pragma unroll
    for (int i = 0; i < 8; ++i) {
        int c = ci*8 + i;
        float s = cn[b*128 + c];
        #pragma unroll
        for (int jj = 0; jj < 8; jj += 4) {
            float4 o4 = make_float4(acc[i][jj]*s, acc[i][jj+1]*s, acc[i][jj+2]*s, acc[i][jj+3]*s);
            *(float4*)&kv[((size_t)b*128 + c)*128 + di*8 + jj] = o4;
        }
    }
}

// ---------------------------------------------------------------- u = v + (q2 @ kv)/27   -> [B,C,NP]
__global__ __launch_bounds__(256) void k_t2u(
    const float* __restrict__ q2, const float* __restrict__ kv,
    const float* __restrict__ v, float* __restrict__ u)
{
    __shared__ __align__(16) float A[64*64];
    __shared__ __align__(16) float W[64*128];
    const int b = blockIdx.y, n0 = blockIdx.x*64, tid = threadIdx.x;
    const int tq = tid & 15, og = tid >> 4;   // d = og*8 .. +8
    float acc[4][8] = {};
    for (int k0 = 0; k0 < 128; k0 += 64) {
        __syncthreads();
        for (int idx = tid; idx < 64*64; idx += 256) {
            int kk = idx >> 6, j = idx & 63;
            int n = n0 + j;
            A[idx] = (n < HN) ? q2[((size_t)b*128 + k0 + kk)*NP + n] : 0.f;
        }
        for (int idx = tid; idx < 64*128; idx += 256) {
            int kk = idx >> 7, d = idx & 127;
            W[idx] = kv[((size_t)b*128 + k0 + kk)*128 + d];
        }
        __syncthreads();
        for (int kk = 0; kk < 64; ++kk) {
            float4 a = *(const float4*)&A[kk*64 + tq*4];
            float4 w0 = *(const float4*)&W[kk*128 + og*8];
            float4 w1 = *(const float4*)&W[kk*128 + og*8 + 4];
            float av[4] = {a.x,a.y,a.z,a.w};
            float wv[8] = {w0.x,w0.y,w0.z,w0.w,w1.x,w1.y,w1.z,w1.w};
            #pragma unroll
            for (int i = 0; i < 4; ++i)
                #pragma unroll
                for (int jj = 0; jj < 8; ++jj)
                    acc[i][jj] += av[i]*wv[jj];
        }
    }
    const float sc = 1.f/27.f;
    const bool full = (n0 + 64 <= HN);
    float vv[4][8];
    #pragma unroll
    for (int i = 0; i < 4; ++i) {
        int n = n0 + tq*4 + i;
        if (n < HN) {
            float4 v0 = *(const float4*)&v[((size_t)b*HN + n)*128 + og*8];
            float4 v1 = *(const float4*)&v[((size_t)b*HN + n)*128 + og*8 + 4];
            vv[i][0]=v0.x; vv[i][1]=v0.y; vv[i][2]=v0.z; vv[i][3]=v0.w;
            vv[i][4]=v1.x; vv[i][5]=v1.y; vv[i][6]=v1.z; vv[i][7]=v1.w;
        }
    }
    if (full) {
        #pragma unroll
        for (int jj = 0; jj < 8; ++jj) {
            int d = og*8 + jj;
            float4 o4 = make_float4(acc[0][jj]*sc + vv[0][jj], acc[1][jj]*sc + vv[1][jj],
                                    acc[2][jj]*sc + vv[2][jj], acc[3][jj]*sc + vv[3][jj]);
            *(float4*)&u[((size_t)b*128 + d)*NP + n0 + tq*4] = o4;
        }
    } else {
        for (int i = 0; i < 4; ++i) {
            int n = n0 + tq*4 + i;
            if (n < HN)
                for (int jj = 0; jj < 8; ++jj)
                    u[((size_t)b*128 + og*8 + jj)*NP + n] = acc[i][jj]*sc + vv[i][jj];
        }
    }
}

// ---------------------------------------------------------------- attn = u @ w_ln + b_ln -> [B,C,NP]
__global__ __launch_bounds__(256) void k_attn(
    const float* __restrict__ u, const float* __restrict__ wln, const float* __restrict__ bln,
    float* __restrict__ attn)
{
    __shared__ __align__(16) float A[64*64];
    __shared__ __align__(16) float W[64*128];
    const int b = blockIdx.y, n0 = blockIdx.x*64, tid = threadIdx.x;
    const int tq = tid & 15, og = tid >> 4;
    float acc[4][8] = {};
    for (int k0 = 0; k0 < 128; k0 += 64) {
        __syncthreads();
        for (int idx = tid; idx < 64*64; idx += 256) {
            int kk = idx >> 6, j = idx & 63;
            int n = n0 + j;
            A[idx] = (n < HN) ? u[((size_t)b*128 + k0 + kk)*NP + n] : 0.f;
        }
        for (int idx = tid; idx < 64*128; idx += 256) {
            int kk = idx >> 7, d = idx & 127;
            W[idx] = wln[(k0+kk)*128 + d];
        }
        __syncthreads();
        for (int kk = 0; kk < 64; ++kk) {
            float4 a = *(const float4*)&A[kk*64 + tq*4];
            float4 w0 = *(const float4*)&W[kk*128 + og*8];
            float4 w1 = *(const float4*)&W[kk*128 + og*8 + 4];
            float av[4] = {a.x,a.y,a.z,a.w};
            float wv[8] = {w0.x,w0.y,w0.z,w0.w,w1.x,w1.y,w1.z,w1.w};
            #pragma unroll
            for (int i = 0; i < 4; ++i)
                #pragma unroll
                for (int jj = 0; jj < 8; ++jj)
                    acc[i][jj] += av[i]*wv[jj];
        }
    }
    const bool full = (n0 + 64 <= HN);
    if (full) {
        #pragma unroll
        for (int jj = 0; jj < 8; ++jj) {
            int d = og*8 + jj;
            float bb = bln[d];
            float4 o4 = make_float4(acc[0][jj]+bb, acc[1][jj]+bb, acc[2][jj]+bb, acc[3][jj]+bb);
            *(float4*)&attn[((size_t)b*128 + d)*NP + n0 + tq*4] = o4;
        }
    } else {
        for (int i = 0; i < 4; ++i) {
            int n = n0 + tq*4 + i;
            if (n < HN)
                for (int jj = 0; jj < 8; ++jj)
                    attn[((size_t)b*128 + og*8 + jj)*NP + n] = acc[i][jj] + bln[og*8+jj];
        }
    }
}

// ---------------------------------------------------------------- ffn1: h = lrelu([x;attn] @ w1 + b1) -> [B,64,NP]
__global__ __launch_bounds__(256) void k_ffn1(
    const float* __restrict__ x, const float* __restrict__ attn,
    const float* __restrict__ w1ft, const float* __restrict__ b1,
    float* __restrict__ h)
{
    __shared__ __align__(16) float A[64*64];
    __shared__ __align__(16) float W[64*64];
    const int b = blockIdx.y, n0 = blockIdx.x*64, tid = threadIdx.x;
    const int tq = tid & 15, og = tid >> 4;
    float acc[4][4];
    #pragma unroll
    for (int i = 0; i < 4; ++i)
        #pragma unroll
        for (int jj = 0; jj < 4; ++jj) acc[i][jj] = b1[og*4 + jj];
    for (int kc = 0; kc < 4; ++kc) {
        __syncthreads();
        if (kc < 2) {
            for (int idx = tid; idx < 4096; idx += 256) {
                int kk = idx >> 6, j = idx & 63; int n = n0 + j;
                A[idx] = (n < HN) ? x[(size_t)(b*128 + kc*64 + kk)*HN + n] : 0.f;
            }
        } else {
            for (int idx = tid; idx < 4096; idx += 256) {
                int kk = idx >> 6, j = idx & 63; int n = n0 + j;
                A[idx] = (n < HN) ? attn[((size_t)b*128 + (kc-2)*64 + kk)*NP + n] : 0.f;
            }
        }
        for (int idx = tid; idx < 4096; idx += 256) {
            int kk = idx >> 6, o = idx & 63;
            W[idx] = w1ft[(kc*64 + kk)*64 + o];
        }
        __syncthreads();
        for (int kk = 0; kk < 64; ++kk) {
            float4 a = *(const float4*)&A[kk*64 + tq*4];
            float4 w = *(const float4*)&W[kk*64 + og*4];
            float av[4] = {a.x,a.y,a.z,a.w};
            float wv[4] = {w.x,w.y,w.z,w.w};
            #pragma unroll
            for (int i = 0; i < 4; ++i)
                #pragma unroll
                for (int jj = 0; jj < 4; ++jj) acc[i][jj] += av[i]*wv[jj];
        }
    }
    #pragma unroll
    for (int i = 0; i < 4; ++i)
        #pragma unroll
        for (int jj = 0; jj < 4; ++jj) {
            float vv = acc[i][jj];
            acc[i][jj] = (vv > 0.f) ? vv : 0.01f*vv;
        }
    const bool full = (n0 + 64 <= HN);
    if (full) {
        #pragma unroll
        for (int jj = 0; jj < 4; ++jj) {
            float4 o4 = make_float4(acc[0][jj], acc[1][jj], acc[2][jj], acc[3][jj]);
            *(float4*)&h[((size_t)b*64 + og*4 + jj)*NP + n0 + tq*4] = o4;
        }
    } else {
        for (int i = 0; i < 4; ++i) {
            int n = n0 + tq*4 + i;
            if (n < HN)
                for (int jj = 0; jj < 4; ++jj)
                    h[((size_t)b*64 + og*4 + jj)*NP + n] = acc[i][jj];
        }
    }
}

// ---------------------------------------------------------------- ffn2: x_en = h @ w2 + b2 + x -> [B,C,NP]
__global__ __launch_bounds__(256) void k_ffn2(
    const float* __restrict__ h, const float* __restrict__ w2ft, const float* __restrict__ b2,
    const float* __restrict__ x, float* __restrict__ xen)
{
    __shared__ __align__(16) float A[64*64];
    __shared__ __align__(16) float W[64*128];
    __shared__ __align__(16) float XT[128*64];
    const int b = blockIdx.y, n0 = blockIdx.x*64, tid = threadIdx.x;
    const int tq = tid & 15, og = tid >> 4;   // c = og*8 .. +8
    for (int idx = tid; idx < 4096; idx += 256) {
        int kk = idx >> 6, j = idx & 63; int n = n0 + j;
        A[idx] = (n < HN) ? h[((size_t)b*64 + kk)*NP + n] : 0.f;
    }
    for (int idx = tid; idx < 8192; idx += 256) W[idx] = w2ft[idx];
    for (int idx = tid; idx < 8192; idx += 256) {
        int c = idx >> 6, j = idx & 63; int n = n0 + j;
        XT[idx] = (n < HN) ? x[(size_t)(b*128 + c)*HN + n] : 0.f;
    }
    __syncthreads();
    float acc[4][8] = {};
    for (int kk = 0; kk < 64; ++kk) {
        float4 a = *(const float4*)&A[kk*64 + tq*4];
        float4 w0 = *(const float4*)&W[kk*128 + og*8];
        float4 w1 = *(const float4*)&W[kk*128 + og*8 + 4];
        float av[4] = {a.x,a.y,a.z,a.w};
        float wv[8] = {w0.x,w0.y,w0.z,w0.w,w1.x,w1.y,w1.z,w1.w};
        #pragma unroll
        for (int i = 0; i < 4; ++i)
            #pragma unroll
            for (int jj = 0; jj < 8; ++jj)
                acc[i][jj] += av[i]*wv[jj];
    }
    const bool full = (n0 + 64 <= HN);
    if (full) {
        #pragma unroll
        for (int jj = 0; jj < 8; ++jj) {
            int c = og*8 + jj;
            float bb = b2[c];
            float r0 = acc[0][jj] + bb + XT[c*64 + tq*4 + 0];
            float r1 = acc[1][jj] + bb + XT[c*64 + tq*4 + 1];
            float r2 = acc[2][jj] + bb + XT[c*64 + tq*4 + 2];
            float r3 = acc[3][jj] + bb + XT[c*64 + tq*4 + 3];
            *(float4*)&xen[((size_t)b*128 + c)*NP + n0 + tq*4] = make_float4(r0,r1,r2,r3);
        }
    } else {
        for (int i = 0; i < 4; ++i) {
            int n = n0 + tq*4 + i;
            if (n < HN)
                for (int jj = 0; jj < 8; ++jj) {
                    int c = og*8 + jj;
                    xen[((size_t)b*128 + c)*NP + n] = acc[i][jj] + b2[c] + XT[c*64 + tq*4 + i];
                }
        }
    }
}

// ---------------------------------------------------------------- conv1 3x3 128->64 + relu + 2x2 pool
// computes 24x24 conv grid (row/col 24 discarded by pool); pool -> [B,12,12,64] NHWC
__global__ __launch_bounds__(256) void k_conv1(
    const float* __restrict__ xen, const float* __restrict__ w1t, const float* __restrict__ bias,
    float* __restrict__ pool1)
{
    __shared__ __align__(16) float XT[16*280];   // [icc][10 rows][28 pitch]
    __shared__ __align__(16) float W[144*64];
    const int b = blockIdx.y;
    const int ty = blockIdx.x * 8;               // 0,8,16
    const int tid = threadIdx.x;
    const int row = tid & 7, og = tid >> 3;      // og 0..31, oc = og*2
    float acc[24][2] = {};
    for (int ic0 = 0; ic0 < 128; ic0 += 16) {
        __syncthreads();
        for (int idx = tid; idx < 4480; idx += 256) {
            int icc = idx / 280; int rem = idx - icc*280;
            int iy = rem / 28, ix = rem - iy*28;
            XT[idx] = (ix < 27) ? xen[((size_t)b*128 + ic0 + icc)*NP + (ty+iy)*27 + ix] : 0.f;
        }
        for (int idx = tid; idx < 9216; idx += 256) W[idx] = w1t[ic0*9*64 + idx];
        __syncthreads();
        for (int icc = 0; icc < 16; ++icc) {
            #pragma unroll
            for (int dy = 0; dy < 3; ++dy) {
                const float* ar = &XT[icc*280 + (row+dy)*28];
                float a[28];
                #pragma unroll
                for (int t = 0; t < 7; ++t) {
                    float4 f = *(const float4*)&ar[t*4];
                    a[t*4]=f.x; a[t*4+1]=f.y; a[t*4+2]=f.z; a[t*4+3]=f.w;
                }
                #pragma unroll
                for (int dx = 0; dx < 3; ++dx) {
                    float2 w = *(const float2*)&W[(icc*9 + dy*3 + dx)*64 + og*2];
                    #pragma unroll
                    for (int px = 0; px < 24; ++px) {
                        acc[px][0] += a[px+dx]*w.x;
                        acc[px][1] += a[px+dx]*w.y;
                    }
                }
            }
        }
    }
    float b0 = bias[og*2], b1 = bias[og*2+1];
    float m[12][2];
    #pragma unroll
    for (int p = 0; p < 12; ++p) {
        float p00 = fmaxf(acc[2*p][0]+b0, 0.f), p10 = fmaxf(acc[2*p+1][0]+b0, 0.f);
        float p01 = fmaxf(acc[2*p][1]+b1, 0.f), p11 = fmaxf(acc[2*p+1][1]+b1, 0.f);
        m[p][0] = fmaxf(p00,p10); m[p][1] = fmaxf(p01,p11);
    }
    #pragma unroll
    for (int p = 0; p < 12; ++p) {
        m[p][0] = fmaxf(m[p][0], __shfl_xor(m[p][0], 1, 64));
        m[p][1] = fmaxf(m[p][1], __shfl_xor(m[p][1], 1, 64));
    }
    if ((row & 1) == 0) {
        int py = (ty + row) >> 1;
        #pragma unroll
        for (int p = 0; p < 12; ++p) {
            *(float2*)&pool1[(((size_t)b*12 + py)*12 + p)*64 + og*2] = make_float2(m[p][0], m[p][1]);
        }
    }
}

// ---------------------------------------------------------------- conv2 3x3 64->128 + relu + pool -> [B,5,5,128]
__global__ __launch_bounds__(256) void k_conv2(
    const float* __restrict__ pool1, const float* __restrict__ w2t, const float* __restrict__ bias,
    float* __restrict__ pool2)
{
    __shared__ __align__(16) float XT[8*144];    // [icc][12*12]
    __shared__ __align__(16) float W[72*32];
    const int b = blockIdx.y;
    const int oc0 = blockIdx.x * 32;
    const int tid = threadIdx.x;
    const int row = tid & 15, og = tid >> 4;     // og 0..15, oc = oc0 + og*2
    float acc[10][2] = {};
    for (int ic0 = 0; ic0 < 64; ic0 += 8) {
        __syncthreads();
        for (int idx = tid; idx < 8*144; idx += 256) {
            int icc = idx & 7, pix = idx >> 3;
            XT[icc*144 + pix] = pool1[((size_t)b*144 + pix)*64 + ic0 + icc];
        }
        for (int idx = tid; idx < 72*32; idx += 256) {
            int r = idx >> 5, o = idx & 31;
            W[idx] = w2t[(ic0*9 + r)*128 + oc0 + o];
        }
        __syncthreads();
        if (row < 10) {
            for (int icc = 0; icc < 8; ++icc) {
                #pragma unroll
                for (int dy = 0; dy < 3; ++dy) {
                    const float* ar = &XT[icc*144 + (row+dy)*12];
                    float a[12];
                    #pragma unroll
                    for (int t = 0; t < 3; ++t) {
                        float4 f = *(const float4*)&ar[t*4];
                        a[t*4]=f.x; a[t*4+1]=f.y; a[t*4+2]=f.z; a[t*4+3]=f.w;
                    }
                    #pragma unroll
                    for (int dx = 0; dx < 3; ++dx) {
                        float2 w = *(const float2*)&W[(icc*9 + dy*3 + dx)*32 + og*2];
                        #pragma unroll
                        for (int px = 0; px < 10; ++px) {
                            acc[px][0] += a[px+dx]*w.x;
                            acc[px][1] += a[px+dx]*w.y;
                        }
                    }
                }
            }
        }
    }
    float b0 = bias[oc0+og*2], b1 = bias[oc0+og*2+1];
    float m[5][2] = {};
    if (row < 10) {
        #pragma unroll
        for (int p = 0; p < 5; ++p) {
            float p00 = fmaxf(acc[2*p][0]+b0, 0.f), p10 = fmaxf(acc[2*p+1][0]+b0, 0.f);
            float p01 = fmaxf(acc[2*p][1]+b1, 0.f), p11 = fmaxf(acc[2*p+1][1]+b1, 0.f);
            m[p][0] = fmaxf(p00,p10); m[p][1] = fmaxf(p01,p11);
        }
    }
    #pragma unroll
    for (int p = 0; p < 5; ++p) {
        m[p][0] = fmaxf(m[p][0], __shfl_xor(m[p][0], 1, 64));
        m[p][1] = fmaxf(m[p][1], __shfl_xor(m[p][1], 1, 64));
    }
    if (row < 10 && (row & 1) == 0) {
        int py = row >> 1;
        #pragma unroll
        for (int p = 0; p < 5; ++p) {
            *(float2*)&pool2[(((size_t)b*5 + py)*5 + p)*128 + oc0 + og*2] = make_float2(m[p][0], m[p][1]);
        }
    }
}

// ---------------------------------------------------------------- NHWC pooled -> NCHW-flatten transposed: o2t[k][b]
__global__ void k_permute(const float* __restrict__ pool2, float* __restrict__ o2t)
{
    int k = blockIdx.x;       // 0..3199, k = c*25 + y*5 + x
    int b = threadIdx.x;      // 0..255
    int c = k / 25, r = k - c*25;
    o2t[(size_t)k*256 + b] = pool2[((size_t)b*25 + r)*128 + c];
}

// ---------------------------------------------------------------- fc1 (K-split partials)
__global__ __launch_bounds__(256) void k_fc1(
    const float* __restrict__ o2t, const float* __restrict__ wfc1, float* __restrict__ part)
{
    __shared__ __align__(16) float A[64*64];
    __shared__ __align__(16) float W[64*64];
    const int m0 = blockIdx.x*64, nn0 = blockIdx.y*64, s = blockIdx.z;
    const int tid = threadIdx.x, tq = tid & 15, og = tid >> 4;
    float acc[4][4] = {};
    for (int chunk = s; chunk < 50; chunk += 4) {
        int k0 = chunk*64;
        __syncthreads();
        for (int idx = tid; idx < 4096; idx += 256) {
            int kk = idx >> 6, mm = idx & 63;
            A[idx] = o2t[(size_t)(k0+kk)*256 + m0 + mm];
        }
        for (int idx = tid; idx < 4096; idx += 256) {
            int kk = idx >> 6, nn = idx & 63;
            W[idx] = wfc1[(size_t)(k0+kk)*512 + nn0 + nn];
        }
        __syncthreads();
        for (int kk = 0; kk < 64; ++kk) {
            float4 a = *(const float4*)&A[kk*64 + tq*4];
            float4 w = *(const float4*)&W[kk*64 + og*4];
            float av[4] = {a.x,a.y,a.z,a.w};
            float wv[4] = {w.x,w.y,w.z,w.w};
            #pragma unroll
            for (int i = 0; i < 4; ++i)
                #pragma unroll
                for (int jj = 0; jj < 4; ++jj) acc[i][jj] += av[i]*wv[jj];
        }
    }
    #pragma unroll
    for (int jn = 0; jn < 4; ++jn) {
        int n = nn0 + og*4 + jn;
        float4 o4 = make_float4(acc[0][jn], acc[1][jn], acc[2][jn], acc[3][jn]);
        *(float4*)&part[((size_t)s*512 + n)*256 + m0 + tq*4] = o4;
    }
}

__global__ void k_fc1red(const float* __restrict__ part, const float* __restrict__ bias,
                         float* __restrict__ o3t)
{
    int idx = blockIdx.x*256 + threadIdx.x;      // 131072 = 512n x 256m
    int n = idx >> 8, m = idx & 255;
    float vs = bias[n];
    #pragma unroll
    for (int s = 0; s < 4; ++s) vs += part[((size_t)s*512 + n)*256 + m];
    o3t[idx] = fmaxf(vs, 0.f);
}

// ---------------------------------------------------------------- fc2
__global__ __launch_bounds__(256) void k_fc2(
    const float* __restrict__ o3t, const float* __restrict__ wfc2, const float* __restrict__ bias,
    float* __restrict__ o4t)
{
    __shared__ __align__(16) float A[64*64];
    __shared__ __align__(16) float W[64*64];
    const int m0 = blockIdx.x*64, nn0 = blockIdx.y*64;
    const int tid = threadIdx.x, tq = tid & 15, og = tid >> 4;
    float acc[4][4] = {};
    for (int k0 = 0; k0 < 512; k0 += 64) {
        __syncthreads();
        for (int idx = tid; idx < 4096; idx += 256) {
            int kk = idx >> 6, mm = idx & 63;
            A[idx] = o3t[(size_t)(k0+kk)*256 + m0 + mm];
        }
        for (int idx = tid; idx < 4096; idx += 256) {
            int kk = idx >> 6, nn = idx & 63;
            W[idx] = wfc2[(size_t)(k0+kk)*512 + nn0 + nn];
        }
        __syncthreads();
        for (int kk = 0; kk < 64; ++kk) {
            float4 a = *(const float4*)&A[kk*64 + tq*4];
            float4 w = *(const float4*)&W[kk*64 + og*4];
            float av[4] = {a.x,a.y,a.z,a.w};
            float wv[4] = {w.x,w.y,w.z,w.w};
            #pragma unroll
            for (int i = 0; i < 4; ++i)
                #pragma unroll
                for (int jj = 0; jj < 4; ++jj) acc[i][jj] += av[i]*wv[jj];
        }
    }
    #pragma unroll
    for (int jn = 0; jn < 4; ++jn) {
        int n = nn0 + og*4 + jn;
        float bb = bias[n];
        float4 o4 = make_float4(fmaxf(acc[0][jn]+bb,0.f), fmaxf(acc[1][jn]+bb,0.f),
                                fmaxf(acc[2][jn]+bb,0.f), fmaxf(acc[3][jn]+bb,0.f));
        *(float4*)&o4t[(size_t)n*256 + m0 + tq*4] = o4;
    }
}

// ---------------------------------------------------------------- classifier head
__global__ __launch_bounds__(256) void k_cls(
    const float* __restrict__ o4t, const float* __restrict__ wcls, const float* __restrict__ bias,
    float* __restrict__ out)
{
    const int tid = threadIdx.x;
    const int ml = tid >> 4, nc = tid & 15;
    const int m = blockIdx.x*16 + ml;
    float acc = bias[nc];
    for (int k = 0; k < 512; ++k)
        acc += o4t[(size_t)k*256 + m] * wcls[k*16 + nc];
    out[m*16 + nc] = acc;
}

// ================================================================ launch
extern "C" void kernel_launch(void* const* d_in, const int* in_sizes, int n_in,
                              void* d_out, int out_size, void* d_ws, size_t ws_size,
                              hipStream_t stream)
{
    (void)in_sizes; (void)n_in; (void)out_size; (void)ws_size;
    const float* x    = (const float*)d_in[0];
    const float* wqkv = (const float*)d_in[1];
    const float* bqkv = (const float*)d_in[2];
    const float* wln  = (const float*)d_in[3];
    const float* bln  = (const float*)d_in[4];
    const float* wff1 = (const float*)d_in[5];
    const float* bff1 = (const float*)d_in[6];
    const float* wff2 = (const float*)d_in[7];
    const float* bff2 = (const float*)d_in[8];
    const float* wc1  = (const float*)d_in[9];
    const float* bc1  = (const float*)d_in[10];
    const float* wc2  = (const float*)d_in[11];
    const float* bc2  = (const float*)d_in[12];
    const float* wfc1 = (const float*)d_in[13];
    const float* bfc1 = (const float*)d_in[14];
    const float* wfc2 = (const float*)d_in[15];
    const float* bfc2 = (const float*)d_in[16];
    const float* wcls = (const float*)d_in[17];
    const float* bcls = (const float*)d_in[18];
    float* out = (float*)d_out;
    float* ws = (float*)d_ws;

    const size_t BUF = (size_t)256*128*NP;       // 23,986,176 floats per big buffer
    float* W0 = ws;
    float* W1 = ws + BUF;
    float* W2 = ws + 2*BUF;
    float* KV = ws + 3*BUF;                      // 256*128*128
    float* CN = KV + (size_t)256*128*128;        // 256*128
    float* w1ft = CN + 256*128;                  // 16384
    float* w2ft = w1ft + 16384;                  // 8192
    float* w1t  = w2ft + 8192;                   // 73728
    float* w2t  = w1t + 73728;                   // 73728
    // total ~76.36M floats (~291 MiB)

    float* q2 = W0; float* k2 = W1; float* v = W2;

    k_prep<<<672, 256, 0, stream>>>(wff1, wff2, wc1, wc2, w1ft, w2ft, w1t, w2t);
    k_qkv<<<dim3(12,256), 256, 0, stream>>>(x, wqkv, bqkv, q2, k2, v);
    k_post_q<<<dim3(3,256), 256, 0, stream>>>(q2);
    k_post_k<<<46656, 256, 0, stream>>>(k2);
    k_colnorm<<<256, 128, 0, stream>>>(k2, CN);
    k_kv<<<256, 256, 0, stream>>>(k2, v, CN, KV);
    float* u = W1;                                // overwrites k2 (dead)
    k_t2u<<<dim3(12,256), 256, 0, stream>>>(q2, KV, v, u);
    float* attn = W0;                             // overwrites q2 (dead)
    k_attn<<<dim3(12,256), 256, 0, stream>>>(u, wln, bln, attn);
    float* h = W2;                                // overwrites v (dead)
    k_ffn1<<<dim3(12,256), 256, 0, stream>>>(x, attn, w1ft, bff1, h);
    float* xen = W1;                              // overwrites u (dead)
    k_ffn2<<<dim3(12,256), 256, 0, stream>>>(h, w2ft, bff2, x, xen);
    float* pool1 = W0;                            // overwrites attn (dead)
    k_conv1<<<dim3(3,256), 256, 0, stream>>>(xen, w1t, bc1, pool1);
    float* pool2 = W2;                            // overwrites h (dead)
    k_conv2<<<dim3(4,256), 256, 0, stream>>>(pool1, w2t, bc2, pool2);
    float* o2t = W0;                              // overwrites pool1 (dead)
    k_permute<<<3200, 256, 0, stream>>>(pool2, o2t);
    float* part = W2;                             // overwrites pool2 (dead)
    k_fc1<<<dim3(4,8,4), 256, 0, stream>>>(o2t, wfc1, part);
    float* o3t = W1;                              // overwrites xen (dead)
    k_fc1red<<<512, 256, 0, stream>>>(part, bfc1, o3t);
    float* o4t = W1 + 131072;                     // disjoint from o3t
    k_fc2<<<dim3(4,8), 256, 0, stream>>>(o3t, wfc2, bfc2, o4t);
    k_cls<<<16, 256, 0, stream>>>(o4t, wcls, bcls, out);
}

// Round 4
// 1126.152 us; speedup vs baseline: 1.8164x; 1.8164x over previous
//
#include <hip/hip_runtime.h>
#include <hip/hip_bf16.h>

#define HB 256
#define HC 128
#define HN 729      // 27*27 tokens
#define NP 732      // fp32 xen row pitch
#define NT2 736     // padded token count for transposed bf16 buffers (16B-aligned rows)

typedef __attribute__((ext_vector_type(8))) short bf16x8;
typedef __attribute__((ext_vector_type(4))) float f32x4;
typedef __attribute__((ext_vector_type(4))) unsigned int uint4v;
typedef unsigned short u16;

#define MFMA16(a,b,c) __builtin_amdgcn_mfma_f32_16x16x32_bf16((a),(b),(c),0,0,0)

__device__ __forceinline__ float wsum(float v) {
    #pragma unroll
    for (int m = 32; m >= 1; m >>= 1) v += __shfl_xor(v, m, 64);
    return v;
}
__device__ __forceinline__ u16 f2b(float f) {
    __hip_bfloat16 h = __float2bfloat16(f);
    return *reinterpret_cast<u16*>(&h);
}
__device__ __forceinline__ float b2f(u16 u) {
    __hip_bfloat16 h;
    *reinterpret_cast<u16*>(&h) = u;
    return __bfloat162float(h);
}
__device__ __forceinline__ unsigned int pk2(u16 a, u16 b) {
    return (unsigned int)a | ((unsigned int)b << 16);
}

// ---- MFMA GEMM building blocks -------------------------------------------
// LDS tile: R rows x 64 k bf16, row pitch 128B, 16B-slot XOR swizzle (slot ^= row&7).
// Source is K-major bf16 [row][srcK]; zero-fill rows >= rowLim or k >= kLim.
__device__ __forceinline__ void stage_tile(char* lds, const u16* src, long srcK,
                                           int row0, int rowLim, int k0, int kLim,
                                           int R, int tid)
{
    for (int t = tid; t < R*8; t += 256) {
        int r = t >> 3, s = t & 7;
        uint4v val = {0u,0u,0u,0u};
        int gr = row0 + r;
        if (gr < rowLim && (k0 + s*8) < kLim)
            val = *(const uint4v*)(src + (long)gr*srcK + k0 + s*8);
        *(uint4v*)(lds + r*128 + ((s ^ (r & 7)) << 4)) = val;
    }
}
// fragment: lane holds row rbase+(lane&15), k = k0 + (lane>>4)*8 .. +8
__device__ __forceinline__ bf16x8 frag_ld(const char* lds, int rbase, int k0, int lane)
{
    int r = rbase + (lane & 15);
    int s = (k0 >> 3) + (lane >> 4);
    return *(const bf16x8*)(lds + r*128 + ((s ^ (r & 7)) << 4));
}

// ---------------------------------------------------------------- weight prep
// w1t[(ic*9+t)*64+oc]  = w_c1[(oc*128+ic)*9+t]      fp32 (conv1)
// w2t[(ic*9+t)*128+oc] = w_c2[(oc*64+ic)*9+t]       fp32 (conv2)
// wqkvT[o][k] = wqkv[k][o]  bf16 [384][128]
// wlnT[c][d]  = wln[d][c]   bf16 [128][128]
// w1b = wff1 [64][256] bf16 ; w2b = wff2 [128][64] bf16
__global__ void k_prep(const float* __restrict__ wf1, const float* __restrict__ wf2,
                       const float* __restrict__ wc1, const float* __restrict__ wc2,
                       const float* __restrict__ wqkv, const float* __restrict__ wln,
                       float* __restrict__ w1t, float* __restrict__ w2t,
                       u16* __restrict__ wqkvT, u16* __restrict__ wlnT,
                       u16* __restrict__ w1b, u16* __restrict__ w2b)
{
    int idx = blockIdx.x*256 + threadIdx.x;
    if (idx < 73728) {
        int row = idx >> 6, oc = idx & 63;
        int ic = row/9, tap = row - ic*9;
        w1t[idx] = wc1[(oc*128 + ic)*9 + tap];
    } else if (idx < 147456) {
        int t = idx - 73728; int row = t >> 7, oc = t & 127;
        int ic = row/9, tap = row - ic*9;
        w2t[t] = wc2[(oc*64 + ic)*9 + tap];
    } else if (idx < 196608) {
        int t = idx - 147456; int o = t >> 7, k = t & 127;
        wqkvT[t] = f2b(wqkv[k*384 + o]);
    } else if (idx < 212992) {
        int t = idx - 196608; int o = t >> 7, k = t & 127;
        wlnT[t] = f2b(wln[k*128 + o]);
    } else if (idx < 229376) {
        int t = idx - 212992;
        w1b[t] = f2b(wf1[t]);
    } else if (idx < 237568) {
        int t = idx - 229376;
        w2b[t] = f2b(wf2[t]);
    }
}

// ---------------------------------------------------------------- x -> bf16 token-major [b][n][128]
__global__ __launch_bounds__(256) void k_xbt(const float* __restrict__ x, u16* __restrict__ xbt)
{
    __shared__ float T[64*129];
    const int b = blockIdx.y, n0 = blockIdx.x*64, tid = threadIdx.x;
    for (int idx = tid; idx < 128*64; idx += 256) {
        int c = idx >> 6, j = idx & 63;
        int n = n0 + j;
        T[j*129 + c] = (n < HN) ? x[(size_t)(b*128 + c)*HN + n] : 0.f;
    }
    __syncthreads();
    for (int idx = tid; idx < 64*16; idx += 256) {
        int m = idx >> 4, cs = idx & 15;
        int n = n0 + m;
        if (n < HN) {
            const float* p = &T[m*129 + cs*8];
            uint4v V = { pk2(f2b(p[0]), f2b(p[1])), pk2(f2b(p[2]), f2b(p[3])),
                         pk2(f2b(p[4]), f2b(p[5])), pk2(f2b(p[6]), f2b(p[7])) };
            *(uint4v*)(xbt + ((long)b*HN + n)*128 + cs*8) = V;
        }
    }
}

// ---------------------------------------------------------------- qkv MFMA: [n][128] x [384][128] -> q,k,v bf16 [n][128]
__global__ __launch_bounds__(256) void k_gqkv(
    const u16* __restrict__ xbt, const u16* __restrict__ wqkvT, const float* __restrict__ bqkv,
    u16* __restrict__ qb, u16* __restrict__ kb, u16* __restrict__ vbt)
{
    __shared__ __align__(16) char smem[8192 + 49152];
    char* As = smem;
    char* Bs = smem + 8192;
    const int b = blockIdx.y, n0 = blockIdx.x*64, tid = threadIdx.x;
    const int lane = tid & 63, w = tid >> 6;
    f32x4 acc[4][6];
    #pragma unroll
    for (int i = 0; i < 4; ++i)
        #pragma unroll
        for (int j = 0; j < 6; ++j) acc[i][j] = (f32x4){0.f,0.f,0.f,0.f};
    const u16* Ab = xbt + (long)b*HN*128;
    for (int kt = 0; kt < 128; kt += 64) {
        stage_tile(As, Ab, 128, n0, HN, kt, 128, 64, tid);
        stage_tile(Bs, wqkvT, 128, 0, 384, kt, 128, 384, tid);
        __syncthreads();
        #pragma unroll
        for (int k0 = 0; k0 < 64; k0 += 32) {
            bf16x8 bf[6];
            #pragma unroll
            for (int j = 0; j < 6; ++j) bf[j] = frag_ld(Bs, (w*6 + j)*16, k0, lane);
            #pragma unroll
            for (int m = 0; m < 4; ++m) {
                bf16x8 af = frag_ld(As, m*16, k0, lane);
                #pragma unroll
                for (int j = 0; j < 6; ++j) acc[m][j] = MFMA16(af, bf[j], acc[m][j]);
            }
        }
        __syncthreads();
    }
    u16* E = (u16*)Bs;   // [64][384]
    #pragma unroll
    for (int m = 0; m < 4; ++m)
        #pragma unroll
        for (int j = 0; j < 6; ++j) {
            int col = w*96 + j*16 + (lane & 15);
            float bia = bqkv[col];
            #pragma unroll
            for (int i = 0; i < 4; ++i) {
                int row = m*16 + (lane >> 4)*4 + i;
                E[row*384 + col] = f2b(acc[m][j][i] + bia);
            }
        }
    __syncthreads();
    for (int t = tid; t < 64*48; t += 256) {
        int r = t / 48, cs = t - r*48;
        int n = n0 + r;
        if (n < HN) {
            int col = cs*8;
            u16* dst = (col < 128) ? qb : (col < 256) ? kb : vbt;
            *(uint4v*)(dst + ((long)b*HN + n)*128 + (col & 127)) = *(const uint4v*)(E + r*384 + col);
        }
    }
}

// ---------------------------------------------------------------- q postprocess (wave per token, in-place -> q2b)
__global__ __launch_bounds__(256) void k_postq(u16* __restrict__ qb)
{
    const int b = blockIdx.y;
    const int n = blockIdx.x*4 + (threadIdx.x >> 6);
    const int lane = threadIdx.x & 63;
    if (n >= HN) return;
    u16* p = qb + ((long)b*HN + n)*128;
    unsigned int u = *(const unsigned int*)(p + 2*lane);
    float f0 = b2f((u16)(u & 0xffff));
    float f1 = b2f((u16)(u >> 16));
    float m = wsum(f0 + f1) * (1.f/128.f);
    float a0 = f0 - m, a1 = f1 - m;
    float s0 = a0*a0, s1 = a1*a1;
    float S  = wsum(s0 + s1);
    float s4 = wsum(s0*s0 + s1*s1);
    float invS = 1.f / (S + 1e-7f);
    float nrm = sqrtf(s4) * invS;
    float sc = invS / fmaxf(nrm, 1e-12f);
    *(unsigned int*)(p + 2*lane) = pk2(f2b(s0*sc), f2b(s1*sc));
}

// ---------------------------------------------------------------- k postprocess + transpose -> k2t [c][NT2]
__global__ __launch_bounds__(256) void k_postk(const u16* __restrict__ kb, u16* __restrict__ k2t)
{
    __shared__ u16 KT[64*130];
    const int b = blockIdx.y, n0 = blockIdx.x*64, tid = threadIdx.x;
    const int lane = tid & 63, w = tid >> 6;
    for (int it = 0; it < 16; ++it) {
        int r = w*16 + it;
        int n = n0 + r;
        float f0 = 0.f, f1 = 0.f;
        if (n < HN) {
            unsigned int u = *(const unsigned int*)(kb + ((long)b*HN + n)*128 + 2*lane);
            f0 = b2f((u16)(u & 0xffff));
            f1 = b2f((u16)(u >> 16));
        }
        float m = wsum(f0 + f1) * (1.f/128.f);
        float a0 = f0 - m, a1 = f1 - m;
        float s0 = a0*a0, s1 = a1*a1;
        float S = wsum(s0 + s1);
        float invS = 1.f/(S + 1e-7f);
        *(unsigned int*)&KT[r*130 + 2*lane] = pk2(f2b(s0*invS), f2b(s1*invS));
    }
    __syncthreads();
    #pragma unroll
    for (int pass = 0; pass < 4; ++pass) {
        int c = pass*32 + (tid >> 3), j8 = tid & 7;
        u16 v[8];
        #pragma unroll
        for (int j = 0; j < 8; ++j) {
            int r = j8*8 + j;
            v[j] = (n0 + r < HN) ? KT[r*130 + c] : (u16)0;
        }
        int n = n0 + j8*8;
        if (n < NT2) {
            uint4v V = { pk2(v[0],v[1]), pk2(v[2],v[3]), pk2(v[4],v[5]), pk2(v[6],v[7]) };
            *(uint4v*)(k2t + ((long)b*128 + c)*NT2 + n) = V;
        }
    }
}

// ---------------------------------------------------------------- v transpose -> vtt [d][NT2]
__global__ __launch_bounds__(256) void k_vT(const u16* __restrict__ vbt, u16* __restrict__ vtt)
{
    __shared__ u16 T[64*130];
    const int b = blockIdx.y, n0 = blockIdx.x*64, tid = threadIdx.x;
    for (int t = tid; t < 64*16; t += 256) {
        int r = t >> 4, cs = t & 15;
        int n = n0 + r;
        uint4v val = {0u,0u,0u,0u};
        if (n < HN) val = *(const uint4v*)(vbt + ((long)b*HN + n)*128 + cs*8);
        #pragma unroll
        for (int e = 0; e < 4; ++e)
            *(unsigned int*)&T[r*130 + cs*8 + e*2] = val[e];
    }
    __syncthreads();
    #pragma unroll
    for (int pass = 0; pass < 4; ++pass) {
        int d = pass*32 + (tid >> 3), j8 = tid & 7;
        u16 v[8];
        #pragma unroll
        for (int j = 0; j < 8; ++j) {
            int r = j8*8 + j;
            v[j] = (n0 + r < HN) ? T[r*130 + d] : (u16)0;
        }
        int n = n0 + j8*8;
        if (n < NT2) {
            uint4v V = { pk2(v[0],v[1]), pk2(v[2],v[3]), pk2(v[4],v[5]), pk2(v[6],v[7]) };
            *(uint4v*)(vtt + ((long)b*128 + d)*NT2 + n) = V;
        }
    }
}

// ---------------------------------------------------------------- column norms of k2 (over tokens)
__global__ __launch_bounds__(256) void k_coln(const u16* __restrict__ k2t, float* __restrict__ cn)
{
    long row = (long)blockIdx.x*4 + (threadIdx.x >> 6);
    int lane = threadIdx.x & 63;
    const u16* p = k2t + row*NT2;
    float s = 0.f;
    for (int i = lane; i < NT2/2; i += 64) {
        unsigned int u = *(const unsigned int*)(p + 2*i);
        float f0 = b2f((u16)(u & 0xffff));
        float f1 = b2f((u16)(u >> 16));
        s += f0*f0 + f1*f1;
    }
    s = wsum(s);
    if (lane == 0) cn[row] = 1.f / fmaxf(sqrtf(s), 1e-12f);
}

// ---------------------------------------------------------------- kvT[d][c] = cn[c] * sum_n v[n][d] k2[n][c]
__global__ __launch_bounds__(256) void k_gkv(
    const u16* __restrict__ vtt, const u16* __restrict__ k2t,
    const float* __restrict__ cn, u16* __restrict__ kvT)
{
    __shared__ __align__(16) char smem[8192 + 16384 + 512];
    char* As = smem;
    char* Bs = smem + 8192;
    float* CNs = (float*)(smem + 8192 + 16384);
    const int b = blockIdx.y, d0 = blockIdx.x*64, tid = threadIdx.x;
    const int lane = tid & 63, w = tid >> 6;
    if (tid < 128) CNs[tid] = cn[b*128 + tid];
    f32x4 acc[4][2];
    #pragma unroll
    for (int i = 0; i < 4; ++i) { acc[i][0] = (f32x4){0,0,0,0}; acc[i][1] = (f32x4){0,0,0,0}; }
    const u16* Ab = vtt + (long)b*128*NT2;
    const u16* Bb = k2t + (long)b*128*NT2;
    for (int kt = 0; kt < NT2; kt += 64) {
        stage_tile(As, Ab, NT2, d0, 128, kt, NT2, 64, tid);
        stage_tile(Bs, Bb, NT2, 0, 128, kt, NT2, 128, tid);
        __syncthreads();
        #pragma unroll
        for (int k0 = 0; k0 < 64; k0 += 32) {
            bf16x8 bf[2];
            bf[0] = frag_ld(Bs, (w*2 + 0)*16, k0, lane);
            bf[1] = frag_ld(Bs, (w*2 + 1)*16, k0, lane);
            #pragma unroll
            for (int m = 0; m < 4; ++m) {
                bf16x8 af = frag_ld(As, m*16, k0, lane);
                acc[m][0] = MFMA16(af, bf[0], acc[m][0]);
                acc[m][1] = MFMA16(af, bf[1], acc[m][1]);
            }
        }
        __syncthreads();
    }
    u16* E = (u16*)Bs;   // [64][128]
    #pragma unroll
    for (int m = 0; m < 4; ++m)
        #pragma unroll
        for (int j = 0; j < 2; ++j) {
            int col = w*32 + j*16 + (lane & 15);
            float s = CNs[col];
            #pragma unroll
            for (int i = 0; i < 4; ++i) {
                int row = m*16 + (lane >> 4)*4 + i;
                E[row*128 + col] = f2b(acc[m][j][i] * s);
            }
        }
    __syncthreads();
    for (int t = tid; t < 64*16; t += 256) {
        int r = t >> 4, cs = t & 15;
        *(uint4v*)(kvT + ((long)b*128 + d0 + r)*128 + cs*8) = *(const uint4v*)(E + r*128 + cs*8);
    }
}

// ---------------------------------------------------------------- u = v + (q2 @ kvT)/27 -> ubt [n][128]
__global__ __launch_bounds__(256) void k_gt2u(
    const u16* __restrict__ q2b, const u16* __restrict__ kvT,
    const u16* __restrict__ vbt, u16* __restrict__ ubt)
{
    __shared__ __align__(16) char smem[8192 + 16384];
    char* As = smem;
    char* Bs = smem + 8192;
    const int b = blockIdx.y, n0 = blockIdx.x*64, tid = threadIdx.x;
    const int lane = tid & 63, w = tid >> 6;
    f32x4 acc[4][2];
    #pragma unroll
    for (int i = 0; i < 4; ++i) { acc[i][0] = (f32x4){0,0,0,0}; acc[i][1] = (f32x4){0,0,0,0}; }
    const u16* Ab = q2b + (long)b*HN*128;
    const u16* Bb = kvT + (long)b*128*128;
    for (int kt = 0; kt < 128; kt += 64) {
        stage_tile(As, Ab, 128, n0, HN, kt, 128, 64, tid);
        stage_tile(Bs, Bb, 128, 0, 128, kt, 128, 128, tid);
        __syncthreads();
        #pragma unroll
        for (int k0 = 0; k0 < 64; k0 += 32) {
            bf16x8 bf[2];
            bf[0] = frag_ld(Bs, (w*2 + 0)*16, k0, lane);
            bf[1] = frag_ld(Bs, (w*2 + 1)*16, k0, lane);
            #pragma unroll
            for (int m = 0; m < 4; ++m) {
                bf16x8 af = frag_ld(As, m*16, k0, lane);
                acc[m][0] = MFMA16(af, bf[0], acc[m][0]);
                acc[m][1] = MFMA16(af, bf[1], acc[m][1]);
            }
        }
        __syncthreads();
    }
    u16* E = (u16*)Bs;
    const float sc = 1.f/27.f;
    #pragma unroll
    for (int m = 0; m < 4; ++m)
        #pragma unroll
        for (int j = 0; j < 2; ++j) {
            int col = w*32 + j*16 + (lane & 15);
            #pragma unroll
            for (int i = 0; i < 4; ++i) {
                int row = m*16 + (lane >> 4)*4 + i;
                E[row*128 + col] = f2b(acc[m][j][i] * sc);
            }
        }
    __syncthreads();
    for (int t = tid; t < 64*16; t += 256) {
        int r = t >> 4, cs = t & 15;
        int n = n0 + r;
        if (n < HN) {
            const u16* ep = E + r*128 + cs*8;
            const u16* vp = vbt + ((long)b*HN + n)*128 + cs*8;
            unsigned int wds[4];
            #pragma unroll
            for (int e = 0; e < 4; ++e)
                wds[e] = pk2(f2b(b2f(ep[e*2]) + b2f(vp[e*2])),
                             f2b(b2f(ep[e*2+1]) + b2f(vp[e*2+1])));
            uint4v V = { wds[0], wds[1], wds[2], wds[3] };
            *(uint4v*)(ubt + ((long)b*HN + n)*128 + cs*8) = V;
        }
    }
}

// ---------------------------------------------------------------- attn = u @ wln + bln -> attnb [n][128]
__global__ __launch_bounds__(256) void k_gattn(
    const u16* __restrict__ ubt, const u16* __restrict__ wlnT, const float* __restrict__ bln,
    u16* __restrict__ attnb)
{
    __shared__ __align__(16) char smem[8192 + 16384 + 512];
    char* As = smem;
    char* Bs = smem + 8192;
    float* BIAS = (float*)(smem + 8192 + 16384);
    const int b = blockIdx.y, n0 = blockIdx.x*64, tid = threadIdx.x;
    const int lane = tid & 63, w = tid >> 6;
    if (tid < 128) BIAS[tid] = bln[tid];
    f32x4 acc[4][2];
    #pragma unroll
    for (int i = 0; i < 4; ++i) { acc[i][0] = (f32x4){0,0,0,0}; acc[i][1] = (f32x4){0,0,0,0}; }
    const u16* Ab = ubt + (long)b*HN*128;
    for (int kt = 0; kt < 128; kt += 64) {
        stage_tile(As, Ab, 128, n0, HN, kt, 128, 64, tid);
        stage_tile(Bs, wlnT, 128, 0, 128, kt, 128, 128, tid);
        __syncthreads();
        #pragma unroll
        for (int k0 = 0; k0 < 64; k0 += 32) {
            bf16x8 bf[2];
            bf[0] = frag_ld(Bs, (w*2 + 0)*16, k0, lane);
            bf[1] = frag_ld(Bs, (w*2 + 1)*16, k0, lane);
            #pragma unroll
            for (int m = 0; m < 4; ++m) {
                bf16x8 af = frag_ld(As, m*16, k0, lane);
                acc[m][0] = MFMA16(af, bf[0], acc[m][0]);
                acc[m][1] = MFMA16(af, bf[1], acc[m][1]);
            }
        }
        __syncthreads();
    }
    u16* E = (u16*)Bs;
    #pragma unroll
    for (int m = 0; m < 4; ++m)
        #pragma unroll
        for (int j = 0; j < 2; ++j) {
            int col = w*32 + j*16 + (lane & 15);
            float bia = BIAS[col];
            #pragma unroll
            for (int i = 0; i < 4; ++i) {
                int row = m*16 + (lane >> 4)*4 + i;
                E[row*128 + col] = f2b(acc[m][j][i] + bia);
            }
        }
    __syncthreads();
    for (int t = tid; t < 64*16; t += 256) {
        int r = t >> 4, cs = t & 15;
        int n = n0 + r;
        if (n < HN)
            *(uint4v*)(attnb + ((long)b*HN + n)*128 + cs*8) = *(const uint4v*)(E + r*128 + cs*8);
    }
}

// ---------------------------------------------------------------- ffn1: h = lrelu([x;attn] @ w1b^T + b1) -> hb [n][64]
__global__ __launch_bounds__(256) void k_gffn1(
    const u16* __restrict__ xbt, const u16* __restrict__ attnb,
    const u16* __restrict__ w1b, const float* __restrict__ b1,
    u16* __restrict__ hb)
{
    __shared__ __align__(16) char smem[8192 + 8192 + 256];
    char* As = smem;
    char* Bs = smem + 8192;
    float* BIAS = (float*)(smem + 16384);
    const int b = blockIdx.y, n0 = blockIdx.x*64, tid = threadIdx.x;
    const int lane = tid & 63, w = tid >> 6;
    if (tid < 64) BIAS[tid] = b1[tid];
    f32x4 acc[4];
    #pragma unroll
    for (int i = 0; i < 4; ++i) acc[i] = (f32x4){0,0,0,0};
    const u16* Ax = xbt + (long)b*HN*128;
    const u16* Aa = attnb + (long)b*HN*128;
    for (int kt = 0; kt < 256; kt += 64) {
        if (kt < 128) stage_tile(As, Ax, 128, n0, HN, kt, 128, 64, tid);
        else          stage_tile(As, Aa, 128, n0, HN, kt - 128, 128, 64, tid);
        stage_tile(Bs, w1b, 256, 0, 64, kt, 256, 64, tid);
        __syncthreads();
        #pragma unroll
        for (int k0 = 0; k0 < 64; k0 += 32) {
            bf16x8 bf = frag_ld(Bs, w*16, k0, lane);
            #pragma unroll
            for (int m = 0; m < 4; ++m) {
                bf16x8 af = frag_ld(As, m*16, k0, lane);
                acc[m] = MFMA16(af, bf, acc[m]);
            }
        }
        __syncthreads();
    }
    u16* E = (u16*)Bs;   // [64][64]
    #pragma unroll
    for (int m = 0; m < 4; ++m) {
        int col = w*16 + (lane & 15);
        float bia = BIAS[col];
        #pragma unroll
        for (int i = 0; i < 4; ++i) {
            int row = m*16 + (lane >> 4)*4 + i;
            float v = acc[m][i] + bia;
            E[row*64 + col] = f2b((v > 0.f) ? v : 0.01f*v);
        }
    }
    __syncthreads();
    for (int t = tid; t < 64*8; t += 256) {
        int r = t >> 3, cs = t & 7;
        int n = n0 + r;
        if (n < HN)
            *(uint4v*)(hb + ((long)b*HN + n)*64 + cs*8) = *(const uint4v*)(E + r*64 + cs*8);
    }
}

// ---------------------------------------------------------------- ffn2: xen = h @ w2b^T + b2 + x -> fp32 [c][NP]
__global__ __launch_bounds__(256) void k_gffn2(
    const u16* __restrict__ hb, const u16* __restrict__ w2b, const float* __restrict__ b2,
    const float* __restrict__ x, float* __restrict__ xen)
{
    __shared__ __align__(16) char smem[8192 + 16384 + 512];
    char* As = smem;
    char* Bs = smem + 8192;
    float* BIAS = (float*)(smem + 8192 + 16384);
    const int b = blockIdx.y, n0 = blockIdx.x*64, tid = threadIdx.x;
    const int lane = tid & 63, w = tid >> 6;
    if (tid < 128) BIAS[tid] = b2[tid];
    f32x4 acc[4][2];
    #pragma unroll
    for (int i = 0; i < 4; ++i) { acc[i][0] = (f32x4){0,0,0,0}; acc[i][1] = (f32x4){0,0,0,0}; }
    const u16* Ab = hb + (long)b*HN*64;
    stage_tile(As, Ab, 64, n0, HN, 0, 64, 64, tid);
    stage_tile(Bs, w2b, 64, 0, 128, 0, 64, 128, tid);
    __syncthreads();
    #pragma unroll
    for (int k0 = 0; k0 < 64; k0 += 32) {
        bf16x8 bf[2];
        bf[0] = frag_ld(Bs, (w*2 + 0)*16, k0, lane);
        bf[1] = frag_ld(Bs, (w*2 + 1)*16, k0, lane);
        #pragma unroll
        for (int m = 0; m < 4; ++m) {
            bf16x8 af = frag_ld(As, m*16, k0, lane);
            acc[m][0] = MFMA16(af, bf[0], acc[m][0]);
            acc[m][1] = MFMA16(af, bf[1], acc[m][1]);
        }
    }
    __syncthreads();
    u16* E = (u16*)Bs;
    #pragma unroll
    for (int m = 0; m < 4; ++m)
        #pragma unroll
        for (int j = 0; j < 2; ++j) {
            int col = w*32 + j*16 + (lane & 15);
            float bia = BIAS[col];
            #pragma unroll
            for (int i = 0; i < 4; ++i) {
                int row = m*16 + (lane >> 4)*4 + i;
                E[row*128 + col] = f2b(acc[m][j][i] + bia);
            }
        }
    __syncthreads();
    // transpose-write + residual: xen[c][n] = E[n-n0][c] + x[c][n]
    // NOTE: x rows have odd length (HN=729) so float2 loads from x can be
    // 4B-misaligned -> use scalar loads (epilogue-only, negligible cost).
    #pragma unroll
    for (int pass = 0; pass < 16; ++pass) {
        int c = pass*8 + (tid >> 5), jj = tid & 31;
        int r = jj*2;
        int n = n0 + r;
        const float* xrow = x + ((long)b*128 + c)*HN;
        float* orow = xen + ((long)b*128 + c)*NP;
        if (n + 1 < HN) {
            float x0 = xrow[n], x1 = xrow[n+1];
            float2 ov;
            ov.x = b2f(E[r*128 + c]) + x0;
            ov.y = b2f(E[(r+1)*128 + c]) + x1;
            *(float2*)(orow + n) = ov;
        } else if (n < HN) {
            orow[n] = b2f(E[r*128 + c]) + xrow[n];
        }
    }
}

// ---------------------------------------------------------------- conv1 3x3 128->64 + relu + 2x2 pool (fp32, unchanged)
__global__ __launch_bounds__(256) void k_conv1(
    const float* __restrict__ xen, const float* __restrict__ w1t, const float* __restrict__ bias,
    float* __restrict__ pool1)
{
    __shared__ __align__(16) float XT[16*280];
    __shared__ __align__(16) float W[144*64];
    const int b = blockIdx.y;
    const int ty = blockIdx.x * 8;
    const int tid = threadIdx.x;
    const int row = tid & 7, og = tid >> 3;
    float acc[24][2] = {};
    for (int ic0 = 0; ic0 < 128; ic0 += 16) {
        __syncthreads();
        for (int idx = tid; idx < 4480; idx += 256) {
            int icc = idx / 280; int rem = idx - icc*280;
            int iy = rem / 28, ix = rem - iy*28;
            XT[idx] = (ix < 27) ? xen[((size_t)b*128 + ic0 + icc)*NP + (ty+iy)*27 + ix] : 0.f;
        }
        for (int idx = tid; idx < 9216; idx += 256) W[idx] = w1t[ic0*9*64 + idx];
        __syncthreads();
        for (int icc = 0; icc < 16; ++icc) {
            #pragma unroll
            for (int dy = 0; dy < 3; ++dy) {
                const float* ar = &XT[icc*280 + (row+dy)*28];
                float a[28];
                #pragma unroll
                for (int t = 0; t < 7; ++t) {
                    float4 f = *(const float4*)&ar[t*4];
                    a[t*4]=f.x; a[t*4+1]=f.y; a[t*4+2]=f.z; a[t*4+3]=f.w;
                }
                #pragma unroll
                for (int dx = 0; dx < 3; ++dx) {
                    float2 wv = *(const float2*)&W[(icc*9 + dy*3 + dx)*64 + og*2];
                    #pragma unroll
                    for (int px = 0; px < 24; ++px) {
                        acc[px][0] += a[px+dx]*wv.x;
                        acc[px][1] += a[px+dx]*wv.y;
                    }
                }
            }
        }
    }
    float b0 = bias[og*2], b1 = bias[og*2+1];
    float m[12][2];
    #pragma unroll
    for (int p = 0; p < 12; ++p) {
        float p00 = fmaxf(acc[2*p][0]+b0, 0.f), p10 = fmaxf(acc[2*p+1][0]+b0, 0.f);
        float p01 = fmaxf(acc[2*p][1]+b1, 0.f), p11 = fmaxf(acc[2*p+1][1]+b1, 0.f);
        m[p][0] = fmaxf(p00,p10); m[p][1] = fmaxf(p01,p11);
    }
    #pragma unroll
    for (int p = 0; p < 12; ++p) {
        m[p][0] = fmaxf(m[p][0], __shfl_xor(m[p][0], 1, 64));
        m[p][1] = fmaxf(m[p][1], __shfl_xor(m[p][1], 1, 64));
    }
    if ((row & 1) == 0) {
        int py = (ty + row) >> 1;
        #pragma unroll
        for (int p = 0; p < 12; ++p)
            *(float2*)&pool1[(((size_t)b*12 + py)*12 + p)*64 + og*2] = make_float2(m[p][0], m[p][1]);
    }
}

// ---------------------------------------------------------------- conv2 3x3 64->128 + relu + pool (fp32, unchanged)
__global__ __launch_bounds__(256) void k_conv2(
    const float* __restrict__ pool1, const float* __restrict__ w2t, const float* __restrict__ bias,
    float* __restrict__ pool2)
{
    __shared__ __align__(16) float XT[8*144];
    __shared__ __align__(16) float W[72*32];
    const int b = blockIdx.y;
    const int oc0 = blockIdx.x * 32;
    const int tid = threadIdx.x;
    const int row = tid & 15, og = tid >> 4;
    float acc[10][2] = {};
    for (int ic0 = 0; ic0 < 64; ic0 += 8) {
        __syncthreads();
        for (int idx = tid; idx < 8*144; idx += 256) {
            int icc = idx & 7, pix = idx >> 3;
            XT[icc*144 + pix] = pool1[((size_t)b*144 + pix)*64 + ic0 + icc];
        }
        for (int idx = tid; idx < 72*32; idx += 256) {
            int r = idx >> 5, o = idx & 31;
            W[idx] = w2t[(ic0*9 + r)*128 + oc0 + o];
        }
        __syncthreads();
        if (row < 10) {
            for (int icc = 0; icc < 8; ++icc) {
                #pragma unroll
                for (int dy = 0; dy < 3; ++dy) {
                    const float* ar = &XT[icc*144 + (row+dy)*12];
                    float a[12];
                    #pragma unroll
                    for (int t = 0; t < 3; ++t) {
                        float4 f = *(const float4*)&ar[t*4];
                        a[t*4]=f.x; a[t*4+1]=f.y; a[t*4+2]=f.z; a[t*4+3]=f.w;
                    }
                    #pragma unroll
                    for (int dx = 0; dx < 3; ++dx) {
                        float2 wv = *(const float2*)&W[(icc*9 + dy*3 + dx)*32 + og*2];
                        #pragma unroll
                        for (int px = 0; px < 10; ++px) {
                            acc[px][0] += a[px+dx]*wv.x;
                            acc[px][1] += a[px+dx]*wv.y;
                        }
                    }
                }
            }
        }
    }
    float b0 = bias[oc0+og*2], b1 = bias[oc0+og*2+1];
    float m[5][2] = {};
    if (row < 10) {
        #pragma unroll
        for (int p = 0; p < 5; ++p) {
            float p00 = fmaxf(acc[2*p][0]+b0, 0.f), p10 = fmaxf(acc[2*p+1][0]+b0, 0.f);
            float p01 = fmaxf(acc[2*p][1]+b1, 0.f), p11 = fmaxf(acc[2*p+1][1]+b1, 0.f);
            m[p][0] = fmaxf(p00,p10); m[p][1] = fmaxf(p01,p11);
        }
    }
    #pragma unroll
    for (int p = 0; p < 5; ++p) {
        m[p][0] = fmaxf(m[p][0], __shfl_xor(m[p][0], 1, 64));
        m[p][1] = fmaxf(m[p][1], __shfl_xor(m[p][1], 1, 64));
    }
    if (row < 10 && (row & 1) == 0) {
        int py = row >> 1;
        #pragma unroll
        for (int p = 0; p < 5; ++p)
            *(float2*)&pool2[(((size_t)b*5 + py)*5 + p)*128 + oc0 + og*2] = make_float2(m[p][0], m[p][1]);
    }
}

// ---------------------------------------------------------------- NHWC pooled -> NCHW-flatten transposed: o2t[k][b]
__global__ void k_permute(const float* __restrict__ pool2, float* __restrict__ o2t)
{
    int k = blockIdx.x;
    int b = threadIdx.x;
    int c = k / 25, r = k - c*25;
    o2t[(size_t)k*256 + b] = pool2[((size_t)b*25 + r)*128 + c];
}

// ---------------------------------------------------------------- fc1 (K-split partials, fp32 unchanged)
__global__ __launch_bounds__(256) void k_fc1(
    const float* __restrict__ o2t, const float* __restrict__ wfc1, float* __restrict__ part)
{
    __shared__ __align__(16) float A[64*64];
    __shared__ __align__(16) float W[64*64];
    const int m0 = blockIdx.x*64, nn0 = blockIdx.y*64, s = blockIdx.z;
    const int tid = threadIdx.x, tq = tid & 15, og = tid >> 4;
    float acc[4][4] = {};
    for (int chunk = s; chunk < 50; chunk += 4) {
        int k0 = chunk*64;
        __syncthreads();
        for (int idx = tid; idx < 4096; idx += 256) {
            int kk = idx >> 6, mm = idx & 63;
            A[idx] = o2t[(size_t)(k0+kk)*256 + m0 + mm];
        }
        for (int idx = tid; idx < 4096; idx += 256) {
            int kk = idx >> 6, nn = idx & 63;
            W[idx] = wfc1[(size_t)(k0+kk)*512 + nn0 + nn];
        }
        __syncthreads();
        for (int kk = 0; kk < 64; ++kk) {
            float4 a = *(const float4*)&A[kk*64 + tq*4];
            float4 wv = *(const float4*)&W[kk*64 + og*4];
            float av[4] = {a.x,a.y,a.z,a.w};
            float wl[4] = {wv.x,wv.y,wv.z,wv.w};
            #pragma unroll
            for (int i = 0; i < 4; ++i)
                #pragma unroll
                for (int jj = 0; jj < 4; ++jj) acc[i][jj] += av[i]*wl[jj];
        }
    }
    #pragma unroll
    for (int jn = 0; jn < 4; ++jn) {
        int n = nn0 + og*4 + jn;
        float4 o4 = make_float4(acc[0][jn], acc[1][jn], acc[2][jn], acc[3][jn]);
        *(float4*)&part[((size_t)s*512 + n)*256 + m0 + tq*4] = o4;
    }
}

__global__ void k_fc1red(const float* __restrict__ part, const float* __restrict__ bias,
                         float* __restrict__ o3t)
{
    int idx = blockIdx.x*256 + threadIdx.x;
    int n = idx >> 8, m = idx & 255;
    float vs = bias[n];
    #pragma unroll
    for (int s = 0; s < 4; ++s) vs += part[((size_t)s*512 + n)*256 + m];
    o3t[idx] = fmaxf(vs, 0.f);
}

// ---------------------------------------------------------------- fc2 (fp32 unchanged)
__global__ __launch_bounds__(256) void k_fc2(
    const float* __restrict__ o3t, const float* __restrict__ wfc2, const float* __restrict__ bias,
    float* __restrict__ o4t)
{
    __shared__ __align__(16) float A[64*64];
    __shared__ __align__(16) float W[64*64];
    const int m0 = blockIdx.x*64, nn0 = blockIdx.y*64;
    const int tid = threadIdx.x, tq = tid & 15, og = tid >> 4;
    float acc[4][4] = {};
    for (int k0 = 0; k0 < 512; k0 += 64) {
        __syncthreads();
        for (int idx = tid; idx < 4096; idx += 256) {
            int kk = idx >> 6, mm = idx & 63;
            A[idx] = o3t[(size_t)(k0+kk)*256 + m0 + mm];
        }
        for (int idx = tid; idx < 4096; idx += 256) {
            int kk = idx >> 6, nn = idx & 63;
            W[idx] = wfc2[(size_t)(k0+kk)*512 + nn0 + nn];
        }
        __syncthreads();
        for (int kk = 0; kk < 64; ++kk) {
            float4 a = *(const float4*)&A[kk*64 + tq*4];
            float4 wv = *(const float4*)&W[kk*64 + og*4];
            float av[4] = {a.x,a.y,a.z,a.w};
            float wl[4] = {wv.x,wv.y,wv.z,wv.w};
            #pragma unroll
            for (int i = 0; i < 4; ++i)
                #pragma unroll
                for (int jj = 0; jj < 4; ++jj) acc[i][jj] += av[i]*wl[jj];
        }
    }
    #pragma unroll
    for (int jn = 0; jn < 4; ++jn) {
        int n = nn0 + og*4 + jn;
        float bb = bias[n];
        float4 o4 = make_float4(fmaxf(acc[0][jn]+bb,0.f), fmaxf(acc[1][jn]+bb,0.f),
                                fmaxf(acc[2][jn]+bb,0.f), fmaxf(acc[3][jn]+bb,0.f));
        *(float4*)&o4t[(size_t)n*256 + m0 + tq*4] = o4;
    }
}

// ---------------------------------------------------------------- classifier head
__global__ __launch_bounds__(256) void k_cls(
    const float* __restrict__ o4t, const float* __restrict__ wcls, const float* __restrict__ bias,
    float* __restrict__ out)
{
    const int tid = threadIdx.x;
    const int ml = tid >> 4, nc = tid & 15;
    const int m = blockIdx.x*16 + ml;
    float acc = bias[nc];
    for (int k = 0; k < 512; ++k)
        acc += o4t[(size_t)k*256 + m] * wcls[k*16 + nc];
    out[m*16 + nc] = acc;
}

// ================================================================ launch
extern "C" void kernel_launch(void* const* d_in, const int* in_sizes, int n_in,
                              void* d_out, int out_size, void* d_ws, size_t ws_size,
                              hipStream_t stream)
{
    (void)in_sizes; (void)n_in; (void)out_size; (void)ws_size;
    const float* x    = (const float*)d_in[0];
    const float* wqkv = (const float*)d_in[1];
    const float* bqkv = (const float*)d_in[2];
    const float* wln  = (const float*)d_in[3];
    const float* bln  = (const float*)d_in[4];
    const float* wff1 = (const float*)d_in[5];
    const float* bff1 = (const float*)d_in[6];
    const float* wff2 = (const float*)d_in[7];
    const float* bff2 = (const float*)d_in[8];
    const float* wc1  = (const float*)d_in[9];
    const float* bc1  = (const float*)d_in[10];
    const float* wc2  = (const float*)d_in[11];
    const float* bc2  = (const float*)d_in[12];
    const float* wfc1 = (const float*)d_in[13];
    const float* bfc1 = (const float*)d_in[14];
    const float* wfc2 = (const float*)d_in[15];
    const float* bfc2 = (const float*)d_in[16];
    const float* wcls = (const float*)d_in[17];
    const float* bcls = (const float*)d_in[18];
    float* out = (float*)d_out;
    char* W = (char*)d_ws;

    // region map (bytes) — total ~297.3 MB (fits: round-0 fp32 version used ~305 MB)
    u16*   ubt   = (u16*)(W + 0);                       // 47,775,744   (dead after attn)
    u16*   xbt   = (u16*)(W + 47775744);                // 47,775,744   (dead after ffn1)
    float* xen   = (float*)(W + 0);                     // 95,944,704   (ffn2 -> conv1; overlays ubt+xbt)
    u16*   qb    = (u16*)(W + 95944704);                // q2b in-place; later attnb
    u16*   attnb = qb;
    float* pool2 = (float*)(W + 95944704);              // after ffn1: conv2 out
    float* o2t   = (float*)(W + 95944704 + 4194304);
    float* part  = (float*)(W + 95944704 + 8388608);
    u16*   kb    = (u16*)(W + 143720448);               // then vtt, then hb, then pool1
    u16*   vtt   = kb;
    u16*   hb    = kb;
    float* pool1 = (float*)(W + 143720448);
    u16*   vbt   = (u16*)(W + 191954944);               // dead after t2u
    float* o3t   = (float*)(W + 191954944);
    float* o4t   = (float*)(W + 191954944 + 1048576);
    u16*   k2t   = (u16*)(W + 239730688);               // 48,234,496
    u16*   kvT   = (u16*)(W + 287965184);               // 8,388,608
    float* cn    = (float*)(W + 296353792);
    float* w1t   = (float*)(W + 296353792 + 131072);
    float* w2t   = (float*)(W + 296353792 + 425984);
    u16*   wqkvT = (u16*)(W + 296353792 + 720896);
    u16*   wlnT  = (u16*)(W + 296353792 + 819200);
    u16*   w1b   = (u16*)(W + 296353792 + 851968);
    u16*   w2b   = (u16*)(W + 296353792 + 884736);

    k_prep<<<928, 256, 0, stream>>>(wff1, wff2, wc1, wc2, wqkv, wln,
                                    w1t, w2t, wqkvT, wlnT, w1b, w2b);
    k_xbt<<<dim3(12,256), 256, 0, stream>>>(x, xbt);
    k_gqkv<<<dim3(12,256), 256, 0, stream>>>(xbt, wqkvT, bqkv, qb, kb, vbt);
    k_postq<<<dim3(183,256), 256, 0, stream>>>(qb);
    k_postk<<<dim3(12,256), 256, 0, stream>>>(kb, k2t);
    k_vT<<<dim3(12,256), 256, 0, stream>>>(vbt, vtt);          // kb dead -> vtt reuses region
    k_coln<<<8192, 256, 0, stream>>>(k2t, cn);
    k_gkv<<<dim3(2,256), 256, 0, stream>>>(vtt, k2t, cn, kvT);
    k_gt2u<<<dim3(12,256), 256, 0, stream>>>(qb, kvT, vbt, ubt);
    k_gattn<<<dim3(12,256), 256, 0, stream>>>(ubt, wlnT, bln, attnb);  // overwrites q2b (dead)
    k_gffn1<<<dim3(12,256), 256, 0, stream>>>(xbt, attnb, w1b, bff1, hb);  // vtt dead -> hb
    k_gffn2<<<dim3(12,256), 256, 0, stream>>>(hb, w2b, bff2, x, xen);  // ubt/xbt dead -> xen
    k_conv1<<<dim3(3,256), 256, 0, stream>>>(xen, w1t, bc1, pool1);    // hb dead -> pool1
    k_conv2<<<dim3(4,256), 256, 0, stream>>>(pool1, w2t, bc2, pool2);  // attnb dead -> pool2
    k_permute<<<3200, 256, 0, stream>>>(pool2, o2t);
    k_fc1<<<dim3(4,8,4), 256, 0, stream>>>(o2t, wfc1, part);
    k_fc1red<<<512, 256, 0, stream>>>(part, bfc1, o3t);                // vbt dead -> o3t
    k_fc2<<<dim3(4,8), 256, 0, stream>>>(o3t, wfc2, bfc2, o4t);
    k_cls<<<16, 256, 0, stream>>>(o4t, wcls, bcls, out);
}

// Round 6
// 949.498 us; speedup vs baseline: 2.1543x; 1.1861x over previous
//
#include <hip/hip_runtime.h>
#include <hip/hip_bf16.h>

#define HB 256
#define HC 128
#define HN 729      // 27*27 tokens
#define NT2 736     // padded token count for transposed bf16 buffers (16B-aligned rows)

typedef __attribute__((ext_vector_type(8))) short bf16x8;
typedef __attribute__((ext_vector_type(4))) float f32x4;
typedef __attribute__((ext_vector_type(4))) unsigned int uint4v;
typedef unsigned short u16;

#define MFMA16(a,b,c) __builtin_amdgcn_mfma_f32_16x16x32_bf16((a),(b),(c),0,0,0)

__device__ __forceinline__ float wsum(float v) {
    #pragma unroll
    for (int m = 32; m >= 1; m >>= 1) v += __shfl_xor(v, m, 64);
    return v;
}
__device__ __forceinline__ u16 f2b(float f) {
    __hip_bfloat16 h = __float2bfloat16(f);
    return *reinterpret_cast<u16*>(&h);
}
__device__ __forceinline__ float b2f(u16 u) {
    __hip_bfloat16 h;
    *reinterpret_cast<u16*>(&h) = u;
    return __bfloat162float(h);
}
__device__ __forceinline__ unsigned int pk2(u16 a, u16 b) {
    return (unsigned int)a | ((unsigned int)b << 16);
}

// ---- MFMA GEMM building blocks -------------------------------------------
// LDS tile: R rows x 64 k bf16, row pitch 128B, 16B-slot XOR swizzle (slot ^= row&7).
__device__ __forceinline__ void stage_tile(char* lds, const u16* src, long srcK,
                                           int row0, int rowLim, int k0, int kLim,
                                           int R, int tid)
{
    for (int t = tid; t < R*8; t += 256) {
        int r = t >> 3, s = t & 7;
        uint4v val = {0u,0u,0u,0u};
        int gr = row0 + r;
        if (gr < rowLim && (k0 + s*8) < kLim)
            val = *(const uint4v*)(src + (long)gr*srcK + k0 + s*8);
        *(uint4v*)(lds + r*128 + ((s ^ (r & 7)) << 4)) = val;
    }
}
// fragment: lane holds row rbase+(lane&15), k = k0 + (lane>>4)*8 .. +8
__device__ __forceinline__ bf16x8 frag_ld(const char* lds, int rbase, int k0, int lane)
{
    int r = rbase + (lane & 15);
    int s = (k0 >> 3) + (lane >> 4);
    return *(const bf16x8*)(lds + r*128 + ((s ^ (r & 7)) << 4));
}

// ---------------------------------------------------------------- weight prep
// w1bT[oc][tap*128+ic] = wc1[(oc*128+ic)*9+tap]   bf16 [64][1152] (conv1 implicit GEMM)
// w2t[(ic*9+t)*128+oc] = wc2[(oc*64+ic)*9+t]      fp32 (conv2)
// wqkvT[o][k] = wqkv[k][o]  bf16 [384][128]
// wlnT[c][d]  = wln[d][c]   bf16 [128][128]
// w1b = wff1 [64][256] bf16 ; w2b = wff2 [128][64] bf16
__global__ void k_prep(const float* __restrict__ wf1, const float* __restrict__ wf2,
                       const float* __restrict__ wc1, const float* __restrict__ wc2,
                       const float* __restrict__ wqkv, const float* __restrict__ wln,
                       u16* __restrict__ w1bT, float* __restrict__ w2t,
                       u16* __restrict__ wqkvT, u16* __restrict__ wlnT,
                       u16* __restrict__ w1b, u16* __restrict__ w2b)
{
    int idx = blockIdx.x*256 + threadIdx.x;
    if (idx < 73728) {
        int o = idx / 1152, k = idx - o*1152;
        int tap = k >> 7, ic = k & 127;
        w1bT[idx] = f2b(wc1[(o*128 + ic)*9 + tap]);
    } else if (idx < 147456) {
        int t = idx - 73728; int row = t >> 7, oc = t & 127;
        int ic = row/9, tap = row - ic*9;
        w2t[t] = wc2[(oc*64 + ic)*9 + tap];
    } else if (idx < 196608) {
        int t = idx - 147456; int o = t >> 7, k = t & 127;
        wqkvT[t] = f2b(wqkv[k*384 + o]);
    } else if (idx < 212992) {
        int t = idx - 196608; int o = t >> 7, k = t & 127;
        wlnT[t] = f2b(wln[k*128 + o]);
    } else if (idx < 229376) {
        int t = idx - 212992;
        w1b[t] = f2b(wf1[t]);
    } else if (idx < 237568) {
        int t = idx - 229376;
        w2b[t] = f2b(wf2[t]);
    }
}

// ---------------------------------------------------------------- x -> bf16 token-major [b][n][128]
__global__ __launch_bounds__(256) void k_xbt(const float* __restrict__ x, u16* __restrict__ xbt)
{
    __shared__ float T[64*129];
    const int b = blockIdx.y, n0 = blockIdx.x*64, tid = threadIdx.x;
    for (int idx = tid; idx < 128*64; idx += 256) {
        int c = idx >> 6, j = idx & 63;
        int n = n0 + j;
        T[j*129 + c] = (n < HN) ? x[(size_t)(b*128 + c)*HN + n] : 0.f;
    }
    __syncthreads();
    for (int idx = tid; idx < 64*16; idx += 256) {
        int m = idx >> 4, cs = idx & 15;
        int n = n0 + m;
        if (n < HN) {
            const float* p = &T[m*129 + cs*8];
            uint4v V = { pk2(f2b(p[0]), f2b(p[1])), pk2(f2b(p[2]), f2b(p[3])),
                         pk2(f2b(p[4]), f2b(p[5])), pk2(f2b(p[6]), f2b(p[7])) };
            *(uint4v*)(xbt + ((long)b*HN + n)*128 + cs*8) = V;
        }
    }
}

// ---------------------------------------------------------------- qkv MFMA: [n][128] x [384][128] -> q,k,v bf16 [n][128]
__global__ __launch_bounds__(256) void k_gqkv(
    const u16* __restrict__ xbt, const u16* __restrict__ wqkvT, const float* __restrict__ bqkv,
    u16* __restrict__ qb, u16* __restrict__ kb, u16* __restrict__ vbt)
{
    __shared__ __align__(16) char smem[8192 + 49152];
    char* As = smem;
    char* Bs = smem + 8192;
    const int b = blockIdx.y, n0 = blockIdx.x*64, tid = threadIdx.x;
    const int lane = tid & 63, w = tid >> 6;
    f32x4 acc[4][6];
    #pragma unroll
    for (int i = 0; i < 4; ++i)
        #pragma unroll
        for (int j = 0; j < 6; ++j) acc[i][j] = (f32x4){0.f,0.f,0.f,0.f};
    const u16* Ab = xbt + (long)b*HN*128;
    for (int kt = 0; kt < 128; kt += 64) {
        stage_tile(As, Ab, 128, n0, HN, kt, 128, 64, tid);
        stage_tile(Bs, wqkvT, 128, 0, 384, kt, 128, 384, tid);
        __syncthreads();
        #pragma unroll
        for (int k0 = 0; k0 < 64; k0 += 32) {
            bf16x8 bf[6];
            #pragma unroll
            for (int j = 0; j < 6; ++j) bf[j] = frag_ld(Bs, (w*6 + j)*16, k0, lane);
            #pragma unroll
            for (int m = 0; m < 4; ++m) {
                bf16x8 af = frag_ld(As, m*16, k0, lane);
                #pragma unroll
                for (int j = 0; j < 6; ++j) acc[m][j] = MFMA16(af, bf[j], acc[m][j]);
            }
        }
        __syncthreads();
    }
    u16* E = (u16*)Bs;   // [64][384]
    #pragma unroll
    for (int m = 0; m < 4; ++m)
        #pragma unroll
        for (int j = 0; j < 6; ++j) {
            int col = w*96 + j*16 + (lane & 15);
            float bia = bqkv[col];
            #pragma unroll
            for (int i = 0; i < 4; ++i) {
                int row = m*16 + (lane >> 4)*4 + i;
                E[row*384 + col] = f2b(acc[m][j][i] + bia);
            }
        }
    __syncthreads();
    for (int t = tid; t < 64*48; t += 256) {
        int r = t / 48, cs = t - r*48;
        int n = n0 + r;
        if (n < HN) {
            int col = cs*8;
            u16* dst = (col < 128) ? qb : (col < 256) ? kb : vbt;
            *(uint4v*)(dst + ((long)b*HN + n)*128 + (col & 127)) = *(const uint4v*)(E + r*384 + col);
        }
    }
}

// ---------------------------------------------------------------- q postprocess (wave per token, in-place -> q2b)
__global__ __launch_bounds__(256) void k_postq(u16* __restrict__ qb)
{
    const int b = blockIdx.y;
    const int n = blockIdx.x*4 + (threadIdx.x >> 6);
    const int lane = threadIdx.x & 63;
    if (n >= HN) return;
    u16* p = qb + ((long)b*HN + n)*128;
    unsigned int u = *(const unsigned int*)(p + 2*lane);
    float f0 = b2f((u16)(u & 0xffff));
    float f1 = b2f((u16)(u >> 16));
    float m = wsum(f0 + f1) * (1.f/128.f);
    float a0 = f0 - m, a1 = f1 - m;
    float s0 = a0*a0, s1 = a1*a1;
    float S  = wsum(s0 + s1);
    float s4 = wsum(s0*s0 + s1*s1);
    float invS = 1.f / (S + 1e-7f);
    float nrm = sqrtf(s4) * invS;
    float sc = invS / fmaxf(nrm, 1e-12f);
    *(unsigned int*)(p + 2*lane) = pk2(f2b(s0*sc), f2b(s1*sc));
}

// ---------------------------------------------------------------- k postprocess + transpose -> k2t [c][NT2]
__global__ __launch_bounds__(256) void k_postk(const u16* __restrict__ kb, u16* __restrict__ k2t)
{
    __shared__ u16 KT[64*130];
    const int b = blockIdx.y, n0 = blockIdx.x*64, tid = threadIdx.x;
    const int lane = tid & 63, w = tid >> 6;
    for (int it = 0; it < 16; ++it) {
        int r = w*16 + it;
        int n = n0 + r;
        float f0 = 0.f, f1 = 0.f;
        if (n < HN) {
            unsigned int u = *(const unsigned int*)(kb + ((long)b*HN + n)*128 + 2*lane);
            f0 = b2f((u16)(u & 0xffff));
            f1 = b2f((u16)(u >> 16));
        }
        float m = wsum(f0 + f1) * (1.f/128.f);
        float a0 = f0 - m, a1 = f1 - m;
        float s0 = a0*a0, s1 = a1*a1;
        float S = wsum(s0 + s1);
        float invS = 1.f/(S + 1e-7f);
        *(unsigned int*)&KT[r*130 + 2*lane] = pk2(f2b(s0*invS), f2b(s1*invS));
    }
    __syncthreads();
    #pragma unroll
    for (int pass = 0; pass < 4; ++pass) {
        int c = pass*32 + (tid >> 3), j8 = tid & 7;
        u16 v[8];
        #pragma unroll
        for (int j = 0; j < 8; ++j) {
            int r = j8*8 + j;
            v[j] = (n0 + r < HN) ? KT[r*130 + c] : (u16)0;
        }
        int n = n0 + j8*8;
        if (n < NT2) {
            uint4v V = { pk2(v[0],v[1]), pk2(v[2],v[3]), pk2(v[4],v[5]), pk2(v[6],v[7]) };
            *(uint4v*)(k2t + ((long)b*128 + c)*NT2 + n) = V;
        }
    }
}

// ---------------------------------------------------------------- v transpose -> vtt [d][NT2]
__global__ __launch_bounds__(256) void k_vT(const u16* __restrict__ vbt, u16* __restrict__ vtt)
{
    __shared__ u16 T[64*130];
    const int b = blockIdx.y, n0 = blockIdx.x*64, tid = threadIdx.x;
    for (int t = tid; t < 64*16; t += 256) {
        int r = t >> 4, cs = t & 15;
        int n = n0 + r;
        uint4v val = {0u,0u,0u,0u};
        if (n < HN) val = *(const uint4v*)(vbt + ((long)b*HN + n)*128 + cs*8);
        #pragma unroll
        for (int e = 0; e < 4; ++e)
            *(unsigned int*)&T[r*130 + cs*8 + e*2] = val[e];
    }
    __syncthreads();
    #pragma unroll
    for (int pass = 0; pass < 4; ++pass) {
        int d = pass*32 + (tid >> 3), j8 = tid & 7;
        u16 v[8];
        #pragma unroll
        for (int j = 0; j < 8; ++j) {
            int r = j8*8 + j;
            v[j] = (n0 + r < HN) ? T[r*130 + d] : (u16)0;
        }
        int n = n0 + j8*8;
        if (n < NT2) {
            uint4v V = { pk2(v[0],v[1]), pk2(v[2],v[3]), pk2(v[4],v[5]), pk2(v[6],v[7]) };
            *(uint4v*)(vtt + ((long)b*128 + d)*NT2 + n) = V;
        }
    }
}

// ---------------------------------------------------------------- column norms of k2 (over tokens)
__global__ __launch_bounds__(256) void k_coln(const u16* __restrict__ k2t, float* __restrict__ cn)
{
    long row = (long)blockIdx.x*4 + (threadIdx.x >> 6);
    int lane = threadIdx.x & 63;
    const u16* p = k2t + row*NT2;
    float s = 0.f;
    for (int i = lane; i < NT2/2; i += 64) {
        unsigned int u = *(const unsigned int*)(p + 2*i);
        float f0 = b2f((u16)(u & 0xffff));
        float f1 = b2f((u16)(u >> 16));
        s += f0*f0 + f1*f1;
    }
    s = wsum(s);
    if (lane == 0) cn[row] = 1.f / fmaxf(sqrtf(s), 1e-12f);
}

// ---------------------------------------------------------------- kvT[d][c] = cn[c] * sum_n v[n][d] k2[n][c]
__global__ __launch_bounds__(256) void k_gkv(
    const u16* __restrict__ vtt, const u16* __restrict__ k2t,
    const float* __restrict__ cn, u16* __restrict__ kvT)
{
    __shared__ __align__(16) char smem[8192 + 16384 + 512];
    char* As = smem;
    char* Bs = smem + 8192;
    float* CNs = (float*)(smem + 8192 + 16384);
    const int b = blockIdx.y, d0 = blockIdx.x*64, tid = threadIdx.x;
    const int lane = tid & 63, w = tid >> 6;
    if (tid < 128) CNs[tid] = cn[b*128 + tid];
    f32x4 acc[4][2];
    #pragma unroll
    for (int i = 0; i < 4; ++i) { acc[i][0] = (f32x4){0,0,0,0}; acc[i][1] = (f32x4){0,0,0,0}; }
    const u16* Ab = vtt + (long)b*128*NT2;
    const u16* Bb = k2t + (long)b*128*NT2;
    for (int kt = 0; kt < NT2; kt += 64) {
        stage_tile(As, Ab, NT2, d0, 128, kt, NT2, 64, tid);
        stage_tile(Bs, Bb, NT2, 0, 128, kt, NT2, 128, tid);
        __syncthreads();
        #pragma unroll
        for (int k0 = 0; k0 < 64; k0 += 32) {
            bf16x8 bf[2];
            bf[0] = frag_ld(Bs, (w*2 + 0)*16, k0, lane);
            bf[1] = frag_ld(Bs, (w*2 + 1)*16, k0, lane);
            #pragma unroll
            for (int m = 0; m < 4; ++m) {
                bf16x8 af = frag_ld(As, m*16, k0, lane);
                acc[m][0] = MFMA16(af, bf[0], acc[m][0]);
                acc[m][1] = MFMA16(af, bf[1], acc[m][1]);
            }
        }
        __syncthreads();
    }
    u16* E = (u16*)Bs;   // [64][128]
    #pragma unroll
    for (int m = 0; m < 4; ++m)
        #pragma unroll
        for (int j = 0; j < 2; ++j) {
            int col = w*32 + j*16 + (lane & 15);
            float s = CNs[col];
            #pragma unroll
            for (int i = 0; i < 4; ++i) {
                int row = m*16 + (lane >> 4)*4 + i;
                E[row*128 + col] = f2b(acc[m][j][i] * s);
            }
        }
    __syncthreads();
    for (int t = tid; t < 64*16; t += 256) {
        int r = t >> 4, cs = t & 15;
        *(uint4v*)(kvT + ((long)b*128 + d0 + r)*128 + cs*8) = *(const uint4v*)(E + r*128 + cs*8);
    }
}

// ---------------------------------------------------------------- u = v + (q2 @ kvT)/27 -> ubt [n][128]
__global__ __launch_bounds__(256) void k_gt2u(
    const u16* __restrict__ q2b, const u16* __restrict__ kvT,
    const u16* __restrict__ vbt, u16* __restrict__ ubt)
{
    __shared__ __align__(16) char smem[8192 + 16384];
    char* As = smem;
    char* Bs = smem + 8192;
    const int b = blockIdx.y, n0 = blockIdx.x*64, tid = threadIdx.x;
    const int lane = tid & 63, w = tid >> 6;
    f32x4 acc[4][2];
    #pragma unroll
    for (int i = 0; i < 4; ++i) { acc[i][0] = (f32x4){0,0,0,0}; acc[i][1] = (f32x4){0,0,0,0}; }
    const u16* Ab = q2b + (long)b*HN*128;
    const u16* Bb = kvT + (long)b*128*128;
    for (int kt = 0; kt < 128; kt += 64) {
        stage_tile(As, Ab, 128, n0, HN, kt, 128, 64, tid);
        stage_tile(Bs, Bb, 128, 0, 128, kt, 128, 128, tid);
        __syncthreads();
        #pragma unroll
        for (int k0 = 0; k0 < 64; k0 += 32) {
            bf16x8 bf[2];
            bf[0] = frag_ld(Bs, (w*2 + 0)*16, k0, lane);
            bf[1] = frag_ld(Bs, (w*2 + 1)*16, k0, lane);
            #pragma unroll
            for (int m = 0; m < 4; ++m) {
                bf16x8 af = frag_ld(As, m*16, k0, lane);
                acc[m][0] = MFMA16(af, bf[0], acc[m][0]);
                acc[m][1] = MFMA16(af, bf[1], acc[m][1]);
            }
        }
        __syncthreads();
    }
    u16* E = (u16*)Bs;
    const float sc = 1.f/27.f;
    #pragma unroll
    for (int m = 0; m < 4; ++m)
        #pragma unroll
        for (int j = 0; j < 2; ++j) {
            int col = w*32 + j*16 + (lane & 15);
            #pragma unroll
            for (int i = 0; i < 4; ++i) {
                int row = m*16 + (lane >> 4)*4 + i;
                E[row*128 + col] = f2b(acc[m][j][i] * sc);
            }
        }
    __syncthreads();
    for (int t = tid; t < 64*16; t += 256) {
        int r = t >> 4, cs = t & 15;
        int n = n0 + r;
        if (n < HN) {
            const u16* ep = E + r*128 + cs*8;
            const u16* vp = vbt + ((long)b*HN + n)*128 + cs*8;
            unsigned int wds[4];
            #pragma unroll
            for (int e = 0; e < 4; ++e)
                wds[e] = pk2(f2b(b2f(ep[e*2]) + b2f(vp[e*2])),
                             f2b(b2f(ep[e*2+1]) + b2f(vp[e*2+1])));
            uint4v V = { wds[0], wds[1], wds[2], wds[3] };
            *(uint4v*)(ubt + ((long)b*HN + n)*128 + cs*8) = V;
        }
    }
}

// ---------------------------------------------------------------- attn = u @ wln + bln -> attnb [n][128]
__global__ __launch_bounds__(256) void k_gattn(
    const u16* __restrict__ ubt, const u16* __restrict__ wlnT, const float* __restrict__ bln,
    u16* __restrict__ attnb)
{
    __shared__ __align__(16) char smem[8192 + 16384 + 512];
    char* As = smem;
    char* Bs = smem + 8192;
    float* BIAS = (float*)(smem + 8192 + 16384);
    const int b = blockIdx.y, n0 = blockIdx.x*64, tid = threadIdx.x;
    const int lane = tid & 63, w = tid >> 6;
    if (tid < 128) BIAS[tid] = bln[tid];
    f32x4 acc[4][2];
    #pragma unroll
    for (int i = 0; i < 4; ++i) { acc[i][0] = (f32x4){0,0,0,0}; acc[i][1] = (f32x4){0,0,0,0}; }
    const u16* Ab = ubt + (long)b*HN*128;
    for (int kt = 0; kt < 128; kt += 64) {
        stage_tile(As, Ab, 128, n0, HN, kt, 128, 64, tid);
        stage_tile(Bs, wlnT, 128, 0, 128, kt, 128, 128, tid);
        __syncthreads();
        #pragma unroll
        for (int k0 = 0; k0 < 64; k0 += 32) {
            bf16x8 bf[2];
            bf[0] = frag_ld(Bs, (w*2 + 0)*16, k0, lane);
            bf[1] = frag_ld(Bs, (w*2 + 1)*16, k0, lane);
            #pragma unroll
            for (int m = 0; m < 4; ++m) {
                bf16x8 af = frag_ld(As, m*16, k0, lane);
                acc[m][0] = MFMA16(af, bf[0], acc[m][0]);
                acc[m][1] = MFMA16(af, bf[1], acc[m][1]);
            }
        }
        __syncthreads();
    }
    u16* E = (u16*)Bs;
    #pragma unroll
    for (int m = 0; m < 4; ++m)
        #pragma unroll
        for (int j = 0; j < 2; ++j) {
            int col = w*32 + j*16 + (lane & 15);
            float bia = BIAS[col];
            #pragma unroll
            for (int i = 0; i < 4; ++i) {
                int row = m*16 + (lane >> 4)*4 + i;
                E[row*128 + col] = f2b(acc[m][j][i] + bia);
            }
        }
    __syncthreads();
    for (int t = tid; t < 64*16; t += 256) {
        int r = t >> 4, cs = t & 15;
        int n = n0 + r;
        if (n < HN)
            *(uint4v*)(attnb + ((long)b*HN + n)*128 + cs*8) = *(const uint4v*)(E + r*128 + cs*8);
    }
}

// ---------------------------------------------------------------- ffn1: h = lrelu([x;attn] @ w1b^T + b1) -> hb [n][64]
__global__ __launch_bounds__(256) void k_gffn1(
    const u16* __restrict__ xbt, const u16* __restrict__ attnb,
    const u16* __restrict__ w1b, const float* __restrict__ b1,
    u16* __restrict__ hb)
{
    __shared__ __align__(16) char smem[8192 + 8192 + 256];
    char* As = smem;
    char* Bs = smem + 8192;
    float* BIAS = (float*)(smem + 16384);
    const int b = blockIdx.y, n0 = blockIdx.x*64, tid = threadIdx.x;
    const int lane = tid & 63, w = tid >> 6;
    if (tid < 64) BIAS[tid] = b1[tid];
    f32x4 acc[4];
    #pragma unroll
    for (int i = 0; i < 4; ++i) acc[i] = (f32x4){0,0,0,0};
    const u16* Ax = xbt + (long)b*HN*128;
    const u16* Aa = attnb + (long)b*HN*128;
    for (int kt = 0; kt < 256; kt += 64) {
        if (kt < 128) stage_tile(As, Ax, 128, n0, HN, kt, 128, 64, tid);
        else          stage_tile(As, Aa, 128, n0, HN, kt - 128, 128, 64, tid);
        stage_tile(Bs, w1b, 256, 0, 64, kt, 256, 64, tid);
        __syncthreads();
        #pragma unroll
        for (int k0 = 0; k0 < 64; k0 += 32) {
            bf16x8 bf = frag_ld(Bs, w*16, k0, lane);
            #pragma unroll
            for (int m = 0; m < 4; ++m) {
                bf16x8 af = frag_ld(As, m*16, k0, lane);
                acc[m] = MFMA16(af, bf, acc[m]);
            }
        }
        __syncthreads();
    }
    u16* E = (u16*)Bs;   // [64][64]
    #pragma unroll
    for (int m = 0; m < 4; ++m) {
        int col = w*16 + (lane & 15);
        float bia = BIAS[col];
        #pragma unroll
        for (int i = 0; i < 4; ++i) {
            int row = m*16 + (lane >> 4)*4 + i;
            float v = acc[m][i] + bia;
            E[row*64 + col] = f2b((v > 0.f) ? v : 0.01f*v);
        }
    }
    __syncthreads();
    for (int t = tid; t < 64*8; t += 256) {
        int r = t >> 3, cs = t & 7;
        int n = n0 + r;
        if (n < HN)
            *(uint4v*)(hb + ((long)b*HN + n)*64 + cs*8) = *(const uint4v*)(E + r*64 + cs*8);
    }
}

// ---------------------------------------------------------------- ffn2: xenb = h @ w2b^T + b2 + x  -> bf16 token-major [n][128]
__global__ __launch_bounds__(256) void k_gffn2(
    const u16* __restrict__ hb, const u16* __restrict__ w2b, const float* __restrict__ b2,
    const float* __restrict__ x, u16* __restrict__ xenb)
{
    __shared__ __align__(16) char smem[8192 + 16384 + 512];
    __shared__ __align__(16) float XT[128*65];   // fp32 x transpose tile, pitch 65
    char* As = smem;
    char* Bs = smem + 8192;
    float* BIAS = (float*)(smem + 8192 + 16384);
    const int b = blockIdx.y, n0 = blockIdx.x*64, tid = threadIdx.x;
    const int lane = tid & 63, w = tid >> 6;
    if (tid < 128) BIAS[tid] = b2[tid];
    // stage residual x tile (coalesced over n, transposed in LDS)
    for (int idx = tid; idx < 8192; idx += 256) {
        int c = idx >> 6, j = idx & 63;
        int n = n0 + j;
        XT[c*65 + j] = (n < HN) ? x[((long)b*128 + c)*HN + n] : 0.f;
    }
    f32x4 acc[4][2];
    #pragma unroll
    for (int i = 0; i < 4; ++i) { acc[i][0] = (f32x4){0,0,0,0}; acc[i][1] = (f32x4){0,0,0,0}; }
    const u16* Ab = hb + (long)b*HN*64;
    stage_tile(As, Ab, 64, n0, HN, 0, 64, 64, tid);
    stage_tile(Bs, w2b, 64, 0, 128, 0, 64, 128, tid);
    __syncthreads();
    #pragma unroll
    for (int k0 = 0; k0 < 64; k0 += 32) {
        bf16x8 bf[2];
        bf[0] = frag_ld(Bs, (w*2 + 0)*16, k0, lane);
        bf[1] = frag_ld(Bs, (w*2 + 1)*16, k0, lane);
        #pragma unroll
        for (int m = 0; m < 4; ++m) {
            bf16x8 af = frag_ld(As, m*16, k0, lane);
            acc[m][0] = MFMA16(af, bf[0], acc[m][0]);
            acc[m][1] = MFMA16(af, bf[1], acc[m][1]);
        }
    }
    __syncthreads();
    u16* E = (u16*)Bs;   // [64][128] bf16 (attn-path + bias)
    #pragma unroll
    for (int m = 0; m < 4; ++m)
        #pragma unroll
        for (int j = 0; j < 2; ++j) {
            int col = w*32 + j*16 + (lane & 15);
            float bia = BIAS[col];
            #pragma unroll
            for (int i = 0; i < 4; ++i) {
                int row = m*16 + (lane >> 4)*4 + i;
                E[row*128 + col] = f2b(acc[m][j][i] + bia);
            }
        }
    __syncthreads();
    // xenb[n][c] = E[r][c] + x[c][n]  (fp32 residual, one bf16 round)
    for (int t = tid; t < 64*16; t += 256) {
        int r = t >> 4, cs = t & 15;
        int n = n0 + r;
        if (n < HN) {
            unsigned int wds[4];
            #pragma unroll
            for (int e = 0; e < 4; ++e) {
                int c0 = cs*8 + e*2;
                float v0 = b2f(E[r*128 + c0])     + XT[c0*65 + r];
                float v1 = b2f(E[r*128 + c0 + 1]) + XT[(c0+1)*65 + r];
                wds[e] = pk2(f2b(v0), f2b(v1));
            }
            uint4v V = { wds[0], wds[1], wds[2], wds[3] };
            *(uint4v*)(xenb + ((long)b*HN + n)*128 + cs*8) = V;
        }
    }
}

// ---------------------------------------------------------------- conv1: implicit-GEMM bf16 MFMA + bias + relu + 2x2 pool
// block = one 8x8 conv-pixel patch x 64 oc; M=64 (pixels), N=64 (oc), K=9 taps x 128 ic
// pool -> pool1 [B,12,12,64] NHWC fp32
__global__ __launch_bounds__(256) void k_gconv1(
    const u16* __restrict__ xenb, const u16* __restrict__ w1bT, const float* __restrict__ bias,
    float* __restrict__ pool1)
{
    __shared__ __align__(16) char smem[64*65*4];   // staging (16KB) / E fp32 [64][65] (16.6KB)
    char* As = smem;
    char* Bs = smem + 8192;
    const int b = blockIdx.y;
    const int patch = blockIdx.x;            // 0..8
    const int py0 = (patch / 3) * 8, px0 = (patch % 3) * 8;
    const int tid = threadIdx.x;
    const int lane = tid & 63, w = tid >> 6;
    const u16* Ximg = xenb + (long)b*HN*128;
    f32x4 acc[4];
    #pragma unroll
    for (int i = 0; i < 4; ++i) acc[i] = (f32x4){0,0,0,0};
    for (int tap = 0; tap < 9; ++tap) {
        const int dy = tap / 3, dx = tap - dy*3;
        #pragma unroll
        for (int kt = 0; kt < 2; ++kt) {
            // stage A: row r -> conv pixel (py0 + r/8 + dy, px0 + r%8 + dx)
            for (int t = tid; t < 512; t += 256) {
                int r = t >> 3, s = t & 7;
                int tok = (py0 + (r >> 3) + dy)*27 + px0 + (r & 7) + dx;
                uint4v val = *(const uint4v*)(Ximg + (long)tok*128 + kt*64 + s*8);
                *(uint4v*)(As + r*128 + ((s ^ (r & 7)) << 4)) = val;
            }
            stage_tile(Bs, w1bT, 1152, 0, 64, tap*128 + kt*64, 1152, 64, tid);
            __syncthreads();
            #pragma unroll
            for (int k0 = 0; k0 < 64; k0 += 32) {
                bf16x8 bf = frag_ld(Bs, w*16, k0, lane);
                #pragma unroll
                for (int m = 0; m < 4; ++m) {
                    bf16x8 af = frag_ld(As, m*16, k0, lane);
                    acc[m] = MFMA16(af, bf, acc[m]);
                }
            }
            __syncthreads();
        }
    }
    // epilogue: bias + relu into fp32 E [64 pixels][65 pitch]
    float* E = (float*)smem;
    {
        int col = w*16 + (lane & 15);
        float bia = bias[col];
        #pragma unroll
        for (int m = 0; m < 4; ++m)
            #pragma unroll
            for (int i = 0; i < 4; ++i) {
                int row = m*16 + (lane >> 4)*4 + i;
                E[row*65 + col] = fmaxf(acc[m][i] + bia, 0.f);
            }
    }
    __syncthreads();
    // 2x2 max pool: 8x8 patch -> 4x4; write NHWC pool1[b][py][px][oc]
    #pragma unroll
    for (int pass = 0; pass < 4; ++pass) {
        int oc = tid & 63;
        int pp = (tid >> 6) + pass*4;        // 0..15
        int pr = pp >> 2, pc = pp & 3;
        int r0 = (2*pr)*8 + 2*pc;
        float v = fmaxf(fmaxf(E[r0*65 + oc], E[(r0+1)*65 + oc]),
                        fmaxf(E[(r0+8)*65 + oc], E[(r0+9)*65 + oc]));
        int py = (py0 >> 1) + pr, px = (px0 >> 1) + pc;
        pool1[(((long)b*12 + py)*12 + px)*64 + oc] = v;
    }
}

// ---------------------------------------------------------------- conv2 3x3 64->128 + relu + pool (fp32, unchanged)
__global__ __launch_bounds__(256) void k_conv2(
    const float* __restrict__ pool1, const float* __restrict__ w2t, const float* __restrict__ bias,
    float* __restrict__ pool2)
{
    __shared__ __align__(16) float XT[8*144];
    __shared__ __align__(16) float W[72*32];
    const int b = blockIdx.y;
    const int oc0 = blockIdx.x * 32;
    const int tid = threadIdx.x;
    const int row = tid & 15, og = tid >> 4;
    float acc[10][2] = {};
    for (int ic0 = 0; ic0 < 64; ic0 += 8) {
        __syncthreads();
        for (int idx = tid; idx < 8*144; idx += 256) {
            int icc = idx & 7, pix = idx >> 3;
            XT[icc*144 + pix] = pool1[((size_t)b*144 + pix)*64 + ic0 + icc];
        }
        for (int idx = tid; idx < 72*32; idx += 256) {
            int r = idx >> 5, o = idx & 31;
            W[idx] = w2t[(ic0*9 + r)*128 + oc0 + o];
        }
        __syncthreads();
        if (row < 10) {
            for (int icc = 0; icc < 8; ++icc) {
                #pragma unroll
                for (int dy = 0; dy < 3; ++dy) {
                    const float* ar = &XT[icc*144 + (row+dy)*12];
                    float a[12];
                    #pragma unroll
                    for (int t = 0; t < 3; ++t) {
                        float4 f = *(const float4*)&ar[t*4];
                        a[t*4]=f.x; a[t*4+1]=f.y; a[t*4+2]=f.z; a[t*4+3]=f.w;
                    }
                    #pragma unroll
                    for (int dx = 0; dx < 3; ++dx) {
                        float2 wv = *(const float2*)&W[(icc*9 + dy*3 + dx)*32 + og*2];
                        #pragma unroll
                        for (int px = 0; px < 10; ++px) {
                            acc[px][0] += a[px+dx]*wv.x;
                            acc[px][1] += a[px+dx]*wv.y;
                        }
                    }
                }
            }
        }
    }
    float b0 = bias[oc0+og*2], b1 = bias[oc0+og*2+1];
    float m[5][2] = {};
    if (row < 10) {
        #pragma unroll
        for (int p = 0; p < 5; ++p) {
            float p00 = fmaxf(acc[2*p][0]+b0, 0.f), p10 = fmaxf(acc[2*p+1][0]+b0, 0.f);
            float p01 = fmaxf(acc[2*p][1]+b1, 0.f), p11 = fmaxf(acc[2*p+1][1]+b1, 0.f);
            m[p][0] = fmaxf(p00,p10); m[p][1] = fmaxf(p01,p11);
        }
    }
    #pragma unroll
    for (int p = 0; p < 5; ++p) {
        m[p][0] = fmaxf(m[p][0], __shfl_xor(m[p][0], 1, 64));
        m[p][1] = fmaxf(m[p][1], __shfl_xor(m[p][1], 1, 64));
    }
    if (row < 10 && (row & 1) == 0) {
        int py = row >> 1;
        #pragma unroll
        for (int p = 0; p < 5; ++p)
            *(float2*)&pool2[(((size_t)b*5 + py)*5 + p)*128 + oc0 + og*2] = make_float2(m[p][0], m[p][1]);
    }
}

// ---------------------------------------------------------------- NHWC pooled -> NCHW-flatten transposed: o2t[k][b]
__global__ void k_permute(const float* __restrict__ pool2, float* __restrict__ o2t)
{
    int k = blockIdx.x;
    int b = threadIdx.x;
    int c = k / 25, r = k - c*25;
    o2t[(size_t)k*256 + b] = pool2[((size_t)b*25 + r)*128 + c];
}

// ---------------------------------------------------------------- fc1 (K-split partials, fp32 unchanged)
__global__ __launch_bounds__(256) void k_fc1(
    const float* __restrict__ o2t, const float* __restrict__ wfc1, float* __restrict__ part)
{
    __shared__ __align__(16) float A[64*64];
    __shared__ __align__(16) float W[64*64];
    const int m0 = blockIdx.x*64, nn0 = blockIdx.y*64, s = blockIdx.z;
    const int tid = threadIdx.x, tq = tid & 15, og = tid >> 4;
    float acc[4][4] = {};
    for (int chunk = s; chunk < 50; chunk += 4) {
        int k0 = chunk*64;
        __syncthreads();
        for (int idx = tid; idx < 4096; idx += 256) {
            int kk = idx >> 6, mm = idx & 63;
            A[idx] = o2t[(size_t)(k0+kk)*256 + m0 + mm];
        }
        for (int idx = tid; idx < 4096; idx += 256) {
            int kk = idx >> 6, nn = idx & 63;
            W[idx] = wfc1[(size_t)(k0+kk)*512 + nn0 + nn];
        }
        __syncthreads();
        for (int kk = 0; kk < 64; ++kk) {
            float4 a = *(const float4*)&A[kk*64 + tq*4];
            float4 wv = *(const float4*)&W[kk*64 + og*4];
            float av[4] = {a.x,a.y,a.z,a.w};
            float wl[4] = {wv.x,wv.y,wv.z,wv.w};
            #pragma unroll
            for (int i = 0; i < 4; ++i)
                #pragma unroll
                for (int jj = 0; jj < 4; ++jj) acc[i][jj] += av[i]*wl[jj];
        }
    }
    #pragma unroll
    for (int jn = 0; jn < 4; ++jn) {
        int n = nn0 + og*4 + jn;
        float4 o4 = make_float4(acc[0][jn], acc[1][jn], acc[2][jn], acc[3][jn]);
        *(float4*)&part[((size_t)s*512 + n)*256 + m0 + tq*4] = o4;
    }
}

__global__ void k_fc1red(const float* __restrict__ part, const float* __restrict__ bias,
                         float* __restrict__ o3t)
{
    int idx = blockIdx.x*256 + threadIdx.x;
    int n = idx >> 8, m = idx & 255;
    float vs = bias[n];
    #pragma unroll
    for (int s = 0; s < 4; ++s) vs += part[((size_t)s*512 + n)*256 + m];
    o3t[idx] = fmaxf(vs, 0.f);
}

// ---------------------------------------------------------------- fc2 (fp32 unchanged)
__global__ __launch_bounds__(256) void k_fc2(
    const float* __restrict__ o3t, const float* __restrict__ wfc2, const float* __restrict__ bias,
    float* __restrict__ o4t)
{
    __shared__ __align__(16) float A[64*64];
    __shared__ __align__(16) float W[64*64];
    const int m0 = blockIdx.x*64, nn0 = blockIdx.y*64;
    const int tid = threadIdx.x, tq = tid & 15, og = tid >> 4;
    float acc[4][4] = {};
    for (int k0 = 0; k0 < 512; k0 += 64) {
        __syncthreads();
        for (int idx = tid; idx < 4096; idx += 256) {
            int kk = idx >> 6, mm = idx & 63;
            A[idx] = o3t[(size_t)(k0+kk)*256 + m0 + mm];
        }
        for (int idx = tid; idx < 4096; idx += 256) {
            int kk = idx >> 6, nn = idx & 63;
            W[idx] = wfc2[(size_t)(k0+kk)*512 + nn0 + nn];
        }
        __syncthreads();
        for (int kk = 0; kk < 64; ++kk) {
            float4 a = *(const float4*)&A[kk*64 + tq*4];
            float4 wv = *(const float4*)&W[kk*64 + og*4];
            float av[4] = {a.x,a.y,a.z,a.w};
            float wl[4] = {wv.x,wv.y,wv.z,wv.w};
            #pragma unroll
            for (int i = 0; i < 4; ++i)
                #pragma unroll
                for (int jj = 0; jj < 4; ++jj) acc[i][jj] += av[i]*wl[jj];
        }
    }
    #pragma unroll
    for (int jn = 0; jn < 4; ++jn) {
        int n = nn0 + og*4 + jn;
        float bb = bias[n];
        float4 o4 = make_float4(fmaxf(acc[0][jn]+bb,0.f), fmaxf(acc[1][jn]+bb,0.f),
                                fmaxf(acc[2][jn]+bb,0.f), fmaxf(acc[3][jn]+bb,0.f));
        *(float4*)&o4t[(size_t)n*256 + m0 + tq*4] = o4;
    }
}

// ---------------------------------------------------------------- classifier head
__global__ __launch_bounds__(256) void k_cls(
    const float* __restrict__ o4t, const float* __restrict__ wcls, const float* __restrict__ bias,
    float* __restrict__ out)
{
    const int tid = threadIdx.x;
    const int ml = tid >> 4, nc = tid & 15;
    const int m = blockIdx.x*16 + ml;
    float acc = bias[nc];
    for (int k = 0; k < 512; ++k)
        acc += o4t[(size_t)k*256 + m] * wcls[k*16 + nc];
    out[m*16 + nc] = acc;
}

// ================================================================ launch
extern "C" void kernel_launch(void* const* d_in, const int* in_sizes, int n_in,
                              void* d_out, int out_size, void* d_ws, size_t ws_size,
                              hipStream_t stream)
{
    (void)in_sizes; (void)n_in; (void)out_size; (void)ws_size;
    const float* x    = (const float*)d_in[0];
    const float* wqkv = (const float*)d_in[1];
    const float* bqkv = (const float*)d_in[2];
    const float* wln  = (const float*)d_in[3];
    const float* bln  = (const float*)d_in[4];
    const float* wff1 = (const float*)d_in[5];
    const float* bff1 = (const float*)d_in[6];
    const float* wff2 = (const float*)d_in[7];
    const float* bff2 = (const float*)d_in[8];
    const float* wc1  = (const float*)d_in[9];
    const float* bc1  = (const float*)d_in[10];
    const float* wc2  = (const float*)d_in[11];
    const float* bc2  = (const float*)d_in[12];
    const float* wfc1 = (const float*)d_in[13];
    const float* bfc1 = (const float*)d_in[14];
    const float* wfc2 = (const float*)d_in[15];
    const float* bfc2 = (const float*)d_in[16];
    const float* wcls = (const float*)d_in[17];
    const float* bcls = (const float*)d_in[18];
    float* out = (float*)d_out;
    char* W = (char*)d_ws;

    // region map (bytes)
    u16*   ubt   = (u16*)(W + 0);                       // 47,775,744  (dead after attn)
    u16*   xenb  = (u16*)(W + 0);                       // ffn2 out -> conv1 in (overlays ubt)
    u16*   xbt   = (u16*)(W + 47775744);                // dead after ffn1
    u16*   qb    = (u16*)(W + 95944704);                // q2b in-place; later attnb
    u16*   attnb = qb;
    float* pool2 = (float*)(W + 95944704);              // conv2 out (attnb dead)
    float* o2t   = (float*)(W + 95944704 + 4194304);
    float* part  = (float*)(W + 95944704 + 8388608);
    u16*   kb    = (u16*)(W + 143720448);               // then vtt, then hb, then pool1
    u16*   vtt   = kb;
    u16*   hb    = kb;
    float* pool1 = (float*)(W + 143720448);             // conv1 out (hb dead)
    u16*   vbt   = (u16*)(W + 191954944);               // dead after t2u
    float* o3t   = (float*)(W + 191954944);
    float* o4t   = (float*)(W + 191954944 + 1048576);
    u16*   k2t   = (u16*)(W + 239730688);               // 48,234,496
    u16*   kvT   = (u16*)(W + 287965184);               // 8,388,608
    float* cn    = (float*)(W + 296353792);
    u16*   w1bT  = (u16*)(W + 296353792 + 131072);      // 147,456 B
    float* w2t   = (float*)(W + 296353792 + 425984);
    u16*   wqkvT = (u16*)(W + 296353792 + 720896);
    u16*   wlnT  = (u16*)(W + 296353792 + 819200);
    u16*   w1b   = (u16*)(W + 296353792 + 851968);
    u16*   w2b   = (u16*)(W + 296353792 + 884736);

    k_prep<<<928, 256, 0, stream>>>(wff1, wff2, wc1, wc2, wqkv, wln,
                                    w1bT, w2t, wqkvT, wlnT, w1b, w2b);
    k_xbt<<<dim3(12,256), 256, 0, stream>>>(x, xbt);
    k_gqkv<<<dim3(12,256), 256, 0, stream>>>(xbt, wqkvT, bqkv, qb, kb, vbt);
    k_postq<<<dim3(183,256), 256, 0, stream>>>(qb);
    k_postk<<<dim3(12,256), 256, 0, stream>>>(kb, k2t);
    k_vT<<<dim3(12,256), 256, 0, stream>>>(vbt, vtt);          // kb dead -> vtt reuses region
    k_coln<<<8192, 256, 0, stream>>>(k2t, cn);
    k_gkv<<<dim3(2,256), 256, 0, stream>>>(vtt, k2t, cn, kvT);
    k_gt2u<<<dim3(12,256), 256, 0, stream>>>(qb, kvT, vbt, ubt);
    k_gattn<<<dim3(12,256), 256, 0, stream>>>(ubt, wlnT, bln, attnb);  // overwrites q2b (dead)
    k_gffn1<<<dim3(12,256), 256, 0, stream>>>(xbt, attnb, w1b, bff1, hb);  // vtt dead -> hb
    k_gffn2<<<dim3(12,256), 256, 0, stream>>>(hb, w2b, bff2, x, xenb); // ubt/xbt dead -> xenb
    k_gconv1<<<dim3(9,256), 256, 0, stream>>>(xenb, w1bT, bc1, pool1); // hb dead -> pool1
    k_conv2<<<dim3(4,256), 256, 0, stream>>>(pool1, w2t, bc2, pool2);  // attnb dead -> pool2
    k_permute<<<3200, 256, 0, stream>>>(pool2, o2t);
    k_fc1<<<dim3(4,8,4), 256, 0, stream>>>(o2t, wfc1, part);
    k_fc1red<<<512, 256, 0, stream>>>(part, bfc1, o3t);                // vbt dead -> o3t
    k_fc2<<<dim3(4,8), 256, 0, stream>>>(o3t, wfc2, bfc2, o4t);
    k_cls<<<16, 256, 0, stream>>>(o4t, wcls, bcls, out);
}